// Round 1
// baseline (197.618 us; speedup 1.0000x reference)
//
#include <hip/hip_runtime.h>
#include <hip/hip_bf16.h>
#include <math.h>

// HGT layer, MI355X. Pipeline:
//  prep_weights : fold rel_att/rel_msg (+rel_pri/sqrt(dk)) into Wk/Wv -> W_all[768,256] bf16
//  cast_h       : h fp32 -> bf16, pad rows [20000,20096) with zeros
//  gemm_qkv     : qkv[20096,768] bf16 = h_bf @ W_all^T + b_eff  (MFMA 16x16x32)
//  CSR build    : deg histogram -> single-block scan -> scatter (stores src per slot)
//  aggregate    : 1 wave/node, single-pass softmax-free normalization:
//                 t = (sum_e exp(q.k')*v') / (sum_e exp(q.k'))
//  gemm_out     : out = (t_bf @ Wa^T + ba)*alpha + h*(1-alpha), alpha=sigmoid(skip)

#define NN   20000
#define NE   320000
#define MPAD 20096   // 157*128

typedef unsigned short u16;
typedef __bf16 bf16x8 __attribute__((ext_vector_type(8)));
typedef float  f32x4  __attribute__((ext_vector_type(4)));

__device__ __forceinline__ float bf2f(u16 x) {
    union { float f; unsigned u; } c; c.u = ((unsigned)x) << 16; return c.f;
}
__device__ __forceinline__ u16 f2bf(float f) {
    union { float f; unsigned u; } c; c.f = f;
    unsigned r = c.u + 0x7fffu + ((c.u >> 16) & 1u);
    return (u16)(r >> 16);
}

__device__ __forceinline__ void gload_lds16(const void* g, void* l) {
    __builtin_amdgcn_global_load_lds(
        (const __attribute__((address_space(1))) unsigned*)g,
        (__attribute__((address_space(3))) unsigned*)l, 16, 0, 0);
}

// ---------------------------------------------------------------- prep weights
// blocks 0..767: row of W_all (0-255 = Wq, 256-511 = rel_att*Wk*scale, 512-767 = rel_msg*Wv)
// blocks 768..1023: cast Wa -> bf16
__global__ void prep_weights(const float* __restrict__ Wq, const float* __restrict__ bq,
                             const float* __restrict__ Wk, const float* __restrict__ bk,
                             const float* __restrict__ Wv, const float* __restrict__ bv,
                             const float* __restrict__ Wa,
                             const float* __restrict__ rel_att, const float* __restrict__ rel_msg,
                             const float* __restrict__ rel_pri,
                             u16* __restrict__ W_all, float* __restrict__ b_eff,
                             u16* __restrict__ Wa_bf)
{
    const int bid = blockIdx.x, t = threadIdx.x;
    if (bid < 768) {
        const int row = bid, col = t;
        float val;
        if (row < 256) {
            val = Wq[row * 256 + col];
            if (col == 0) b_eff[row] = bq[row];
        } else if (row < 512) {
            const int r = row - 256, hh = r >> 5, e = r & 31;
            const float s = rel_pri[hh] * 0.17677669529663687f; // 1/sqrt(32)
            float acc = 0.f;
            for (int d = 0; d < 32; ++d)
                acc += rel_att[hh * 1024 + d * 32 + e] * Wk[(hh * 32 + d) * 256 + col];
            val = acc * s;
            if (col == 0) {
                float b = 0.f;
                for (int d = 0; d < 32; ++d) b += rel_att[hh * 1024 + d * 32 + e] * bk[hh * 32 + d];
                b_eff[row] = b * s;
            }
        } else {
            const int r = row - 512, hh = r >> 5, e = r & 31;
            float acc = 0.f;
            for (int d = 0; d < 32; ++d)
                acc += rel_msg[hh * 1024 + d * 32 + e] * Wv[(hh * 32 + d) * 256 + col];
            val = acc;
            if (col == 0) {
                float b = 0.f;
                for (int d = 0; d < 32; ++d) b += rel_msg[hh * 1024 + d * 32 + e] * bv[hh * 32 + d];
                b_eff[row] = b;
            }
        }
        W_all[row * 256 + col] = f2bf(val);
    } else {
        const int idx = (bid - 768) * 256 + t; // 0..65535
        Wa_bf[idx] = f2bf(Wa[idx]);
    }
}

// ---------------------------------------------------------------- cast h (pad to MPAD rows)
__global__ void cast_h(const float* __restrict__ h, u16* __restrict__ hb)
{
    const int i = blockIdx.x * 256 + threadIdx.x;  // one ushort4 per thread
    const int row = i >> 6, c4 = (i & 63) * 4;
    if (row >= MPAD) return;
    ushort4 o;
    if (row < NN) {
        const float4 v = *(const float4*)(h + (size_t)row * 256 + c4);
        o.x = f2bf(v.x); o.y = f2bf(v.y); o.z = f2bf(v.z); o.w = f2bf(v.w);
    } else {
        o = make_ushort4(0, 0, 0, 0);
    }
    *(ushort4*)(hb + (size_t)row * 256 + c4) = o;
}

// ---------------------------------------------------------------- GEMM qkv (C bf16, +bias)
// A[MPAD,256] bf16, B[768,256] bf16 (row = output col), C[MPAD,768] bf16
__global__ __launch_bounds__(256) void gemm_qkv(
    const u16* __restrict__ A, const u16* __restrict__ B,
    const float* __restrict__ bias, u16* __restrict__ C)
{
    __shared__ u16 At[128 * 64];
    __shared__ u16 Bt[128 * 64];
    const int t = threadIdx.x;
    const int wave = t >> 6, lane = t & 63;
    const int row0 = blockIdx.x * 128, col0 = blockIdx.y * 128;
    const int wm = (wave >> 1) * 64, wn = (wave & 1) * 64;
    const int cl = lane & 15, rh = lane >> 4;
    const int srow = t >> 3;           // staging row (within 32-row group), +32 per round
    const int scol = (t & 7) * 8;      // staging col (elements)

    f32x4 acc[4][4] = {};

    for (int k0 = 0; k0 < 256; k0 += 64) {
        __syncthreads();
        #pragma unroll
        for (int r = 0; r < 4; ++r) {
            const int rowT = r * 32 + srow;
            gload_lds16(A + (size_t)(row0 + rowT) * 256 + k0 + scol, &At[(r * 256 + wave * 64) * 8]);
            gload_lds16(B + (size_t)(col0 + rowT) * 256 + k0 + scol, &Bt[(r * 256 + wave * 64) * 8]);
        }
        __syncthreads();
        #pragma unroll
        for (int kk = 0; kk < 64; kk += 32) {
            bf16x8 af[4], bb[4];
            #pragma unroll
            for (int m = 0; m < 4; ++m)
                af[m] = *(const bf16x8*)&At[(wm + 16 * m + cl) * 64 + kk + rh * 8];
            #pragma unroll
            for (int n = 0; n < 4; ++n)
                bb[n] = *(const bf16x8*)&Bt[(wn + 16 * n + cl) * 64 + kk + rh * 8];
            #pragma unroll
            for (int m = 0; m < 4; ++m)
                #pragma unroll
                for (int n = 0; n < 4; ++n)
                    acc[m][n] = __builtin_amdgcn_mfma_f32_16x16x32_bf16(af[m], bb[n], acc[m][n], 0, 0, 0);
        }
    }
    #pragma unroll
    for (int n = 0; n < 4; ++n) {
        const int col = col0 + wn + 16 * n + cl;
        const float bv = bias[col];
        #pragma unroll
        for (int m = 0; m < 4; ++m) {
            const int rowb = row0 + wm + 16 * m + 4 * rh;
            #pragma unroll
            for (int r = 0; r < 4; ++r)
                C[(size_t)(rowb + r) * 768 + col] = f2bf(acc[m][n][r] + bv);
        }
    }
}

// ---------------------------------------------------------------- GEMM out (fp32, residual)
__global__ __launch_bounds__(256) void gemm_out(
    const u16* __restrict__ A, const u16* __restrict__ B,
    const float* __restrict__ bias, const float* __restrict__ hres,
    const float* __restrict__ skip, float* __restrict__ C)
{
    __shared__ u16 At[128 * 64];
    __shared__ u16 Bt[128 * 64];
    const int t = threadIdx.x;
    const int wave = t >> 6, lane = t & 63;
    const int row0 = blockIdx.x * 128, col0 = blockIdx.y * 128;
    const int wm = (wave >> 1) * 64, wn = (wave & 1) * 64;
    const int cl = lane & 15, rh = lane >> 4;
    const int srow = t >> 3, scol = (t & 7) * 8;

    f32x4 acc[4][4] = {};

    for (int k0 = 0; k0 < 256; k0 += 64) {
        __syncthreads();
        #pragma unroll
        for (int r = 0; r < 4; ++r) {
            const int rowT = r * 32 + srow;
            gload_lds16(A + (size_t)(row0 + rowT) * 256 + k0 + scol, &At[(r * 256 + wave * 64) * 8]);
            gload_lds16(B + (size_t)(col0 + rowT) * 256 + k0 + scol, &Bt[(r * 256 + wave * 64) * 8]);
        }
        __syncthreads();
        #pragma unroll
        for (int kk = 0; kk < 64; kk += 32) {
            bf16x8 af[4], bb[4];
            #pragma unroll
            for (int m = 0; m < 4; ++m)
                af[m] = *(const bf16x8*)&At[(wm + 16 * m + cl) * 64 + kk + rh * 8];
            #pragma unroll
            for (int n = 0; n < 4; ++n)
                bb[n] = *(const bf16x8*)&Bt[(wn + 16 * n + cl) * 64 + kk + rh * 8];
            #pragma unroll
            for (int m = 0; m < 4; ++m)
                #pragma unroll
                for (int n = 0; n < 4; ++n)
                    acc[m][n] = __builtin_amdgcn_mfma_f32_16x16x32_bf16(af[m], bb[n], acc[m][n], 0, 0, 0);
        }
    }
    const float alpha = 1.f / (1.f + __expf(-skip[0]));
    const float beta = 1.f - alpha;
    #pragma unroll
    for (int n = 0; n < 4; ++n) {
        const int col = col0 + wn + 16 * n + cl;
        const float bv = bias[col];
        #pragma unroll
        for (int m = 0; m < 4; ++m) {
            const int rowb = row0 + wm + 16 * m + 4 * rh;
            #pragma unroll
            for (int r = 0; r < 4; ++r) {
                const int row = rowb + r;
                if (row < NN)
                    C[(size_t)row * 256 + col] =
                        (acc[m][n][r] + bv) * alpha + hres[(size_t)row * 256 + col] * beta;
            }
        }
    }
}

// ---------------------------------------------------------------- CSR build
__global__ void deg_count(const int* __restrict__ dst, int* __restrict__ deg)
{
    const int e = blockIdx.x * 256 + threadIdx.x;
    if (e < NE) atomicAdd(&deg[dst[e]], 1);
}

__global__ void scan_deg(const int* __restrict__ deg, int* __restrict__ off, int* __restrict__ cur)
{
    __shared__ int sd[1024];
    __shared__ int carry;
    const int t = threadIdx.x;
    if (t == 0) carry = 0;
    __syncthreads();
    for (int base = 0; base < NN; base += 1024) {
        const int i = base + t;
        const int v = (i < NN) ? deg[i] : 0;
        sd[t] = v;
        __syncthreads();
        for (int ofs = 1; ofs < 1024; ofs <<= 1) {
            const int add = (t >= ofs) ? sd[t - ofs] : 0;
            __syncthreads();
            sd[t] += add;
            __syncthreads();
        }
        const int excl = sd[t] - v + carry;
        if (i < NN) { off[i] = excl; cur[i] = excl; }
        __syncthreads();
        if (t == 1023) carry += sd[1023];
        __syncthreads();
    }
    if (t == 0) off[NN] = carry;
}

__global__ void scatter_edges(const int* __restrict__ dst, const int* __restrict__ src,
                              int* __restrict__ cur, int* __restrict__ esrc)
{
    const int e = blockIdx.x * 256 + threadIdx.x;
    if (e < NE) {
        const int p = atomicAdd(&cur[dst[e]], 1);
        esrc[p] = src[e];  // store src id directly; edge id itself never needed again
    }
}

// ---------------------------------------------------------------- aggregation (1 wave / node)
// lane l owns elements 4l..4l+3 of the 256-dim row; head of lane = l>>3.
__global__ __launch_bounds__(256) void aggregate(
    const u16* __restrict__ qkv, const int* __restrict__ off,
    const int* __restrict__ esrc, u16* __restrict__ tout)
{
    const int wid = blockIdx.x * 4 + (threadIdx.x >> 6);
    const int lane = threadIdx.x & 63;
    if (wid >= MPAD) return;
    if (wid >= NN) {  // zero pad rows for the downstream GEMM
        *(ushort4*)(tout + (size_t)wid * 256 + lane * 4) = make_ushort4(0, 0, 0, 0);
        return;
    }
    const ushort4 qv = *(const ushort4*)(qkv + (size_t)wid * 768 + lane * 4);
    const float q0 = bf2f(qv.x), q1 = bf2f(qv.y), q2 = bf2f(qv.z), q3 = bf2f(qv.w);
    float a0 = 0.f, a1 = 0.f, a2 = 0.f, a3 = 0.f, z = 0.f;
    const int e0 = off[wid], e1 = off[wid + 1];
    for (int i = e0; i < e1; ++i) {
        const int s = esrc[i];
        const u16* base = qkv + (size_t)s * 768;
        const ushort4 kv = *(const ushort4*)(base + 256 + lane * 4);
        const ushort4 vv = *(const ushort4*)(base + 512 + lane * 4);
        float p = q0 * bf2f(kv.x) + q1 * bf2f(kv.y) + q2 * bf2f(kv.z) + q3 * bf2f(kv.w);
        p += __shfl_xor(p, 1);
        p += __shfl_xor(p, 2);
        p += __shfl_xor(p, 4);   // all 8 lanes of the head now hold the full dot
        const float ex = __expf(p);  // scale rel_pri/sqrt(dk) already folded into k
        z += ex;
        a0 += ex * bf2f(vv.x); a1 += ex * bf2f(vv.y);
        a2 += ex * bf2f(vv.z); a3 += ex * bf2f(vv.w);
    }
    const float rz = (z > 0.f) ? 1.f / z : 0.f;
    ushort4 o;
    o.x = f2bf(a0 * rz); o.y = f2bf(a1 * rz); o.z = f2bf(a2 * rz); o.w = f2bf(a3 * rz);
    *(ushort4*)(tout + (size_t)wid * 256 + lane * 4) = o;
}

// ---------------------------------------------------------------- launch
extern "C" void kernel_launch(void* const* d_in, const int* in_sizes, int n_in,
                              void* d_out, int out_size, void* d_ws, size_t ws_size,
                              hipStream_t stream)
{
    const float* h   = (const float*)d_in[0];
    const int*   src = (const int*)d_in[1];
    const int*   dst = (const int*)d_in[2];
    const float* Wk  = (const float*)d_in[3];
    const float* bk  = (const float*)d_in[4];
    const float* Wq  = (const float*)d_in[5];
    const float* bq  = (const float*)d_in[6];
    const float* Wv  = (const float*)d_in[7];
    const float* bv  = (const float*)d_in[8];
    const float* Wa  = (const float*)d_in[9];
    const float* ba  = (const float*)d_in[10];
    const float* rel_att = (const float*)d_in[11];
    const float* rel_msg = (const float*)d_in[12];
    const float* rel_pri = (const float*)d_in[13];
    const float* skip    = (const float*)d_in[14];
    float* out = (float*)d_out;

    char* w = (char*)d_ws;
    // ws layout (bytes), ~43.2 MB total:
    u16*   h_bf  = (u16*)(w + 0);           // MPAD*256*2 = 10,289,152
    u16*   W_all = (u16*)(w + 10289152);    // 768*256*2  =    393,216
    float* b_eff = (float*)(w + 10682368);  // 768*4      =      3,072 (+pad)
    u16*   Wa_bf = (u16*)(w + 10685440);    // 256*256*2  =    131,072
    u16*   qkv   = (u16*)(w + 10816512);    // MPAD*768*2 = 30,867,456
    int*   deg   = (int*)(w + 41683968);    // 20000*4    ->     80,128
    int*   off   = (int*)(w + 41764096);    // 20001*4    ->     80,128
    int*   cur   = (int*)(w + 41844224);    //                   80,128
    int*   esrc  = (int*)(w + 41924352);    // NE*4       =  1,280,000
    u16*   t_bf  = h_bf;                    // alias: h_bf dead after gemm_qkv

    (void)hipMemsetAsync(deg, 0, NN * sizeof(int), stream);
    prep_weights<<<1024, 256, 0, stream>>>(Wq, bq, Wk, bk, Wv, bv, Wa,
                                           rel_att, rel_msg, rel_pri, W_all, b_eff, Wa_bf);
    cast_h<<<MPAD * 64 / 256, 256, 0, stream>>>(h, h_bf);
    gemm_qkv<<<dim3(157, 6), 256, 0, stream>>>(h_bf, W_all, b_eff, qkv);
    deg_count<<<NE / 256, 256, 0, stream>>>(dst, deg);
    scan_deg<<<1, 1024, 0, stream>>>(deg, off, cur);
    scatter_edges<<<NE / 256, 256, 0, stream>>>(dst, src, cur, esrc);
    aggregate<<<MPAD / 4, 256, 0, stream>>>(qkv, off, esrc, t_bf);
    gemm_out<<<dim3(157, 2), 256, 0, stream>>>(t_bf, Wa_bf, ba, h, skip, out);
}

// Round 2
// 160.519 us; speedup vs baseline: 1.2311x; 1.2311x over previous
//
#include <hip/hip_runtime.h>
#include <hip/hip_bf16.h>
#include <math.h>

// HGT layer, MI355X. Pipeline:
//  prep_all     : fold rel_att/rel_msg (+rel_pri*log2e/sqrt(dk)) into Wk/Wv -> W_all[768,256] bf16
//                 + cast h fp32->bf16 (pad rows [20000,20096) = 0)
//  gemm_qkv     : qkv[20096,768] bf16 = h_bf @ W_all^T + b_eff  (MFMA 16x16x32)
//  CSR build    : deg histogram -> wave-shuffle scan -> scatter (stores src per slot)
//  aggregate    : 1 wave/node, half-wave per edge, ids bulk-loaded, 4 gathers in flight:
//                 t = (sum_e exp2(q.k')*v') / (sum_e exp2(q.k'))   [log2e folded into k]
//  gemm_out     : out = (t_bf @ Wa^T + ba)*alpha + h*(1-alpha), alpha=sigmoid(skip)

#define NN   20000
#define NE   320000
#define MPAD 20096   // 157*128

typedef unsigned short u16;
typedef __bf16 bf16x8 __attribute__((ext_vector_type(8)));
typedef u16    u16x8  __attribute__((ext_vector_type(8)));
typedef float  f32x4  __attribute__((ext_vector_type(4)));

__device__ __forceinline__ float bf2f(u16 x) {
    union { float f; unsigned u; } c; c.u = ((unsigned)x) << 16; return c.f;
}
__device__ __forceinline__ u16 f2bf(float f) {
    union { float f; unsigned u; } c; c.f = f;
    unsigned r = c.u + 0x7fffu + ((c.u >> 16) & 1u);
    return (u16)(r >> 16);
}

__device__ __forceinline__ void gload_lds16(const void* g, void* l) {
    __builtin_amdgcn_global_load_lds(
        (const __attribute__((address_space(1))) unsigned*)g,
        (__attribute__((address_space(3))) unsigned*)l, 16, 0, 0);
}

// ---------------------------------------------------------------- prep (weights + h cast)
// blocks 0..767   : row of W_all (0-255 Wq, 256-511 rel_att*Wk*scale, 512-767 rel_msg*Wv)
// blocks 768..1023: cast Wa -> bf16
// blocks 1024..   : cast h -> bf16, pad rows zeroed (one ushort4 per thread)
__global__ void prep_all(const float* __restrict__ Wq, const float* __restrict__ bq,
                         const float* __restrict__ Wk, const float* __restrict__ bk,
                         const float* __restrict__ Wv, const float* __restrict__ bv,
                         const float* __restrict__ Wa,
                         const float* __restrict__ rel_att, const float* __restrict__ rel_msg,
                         const float* __restrict__ rel_pri,
                         const float* __restrict__ h,
                         u16* __restrict__ W_all, float* __restrict__ b_eff,
                         u16* __restrict__ Wa_bf, u16* __restrict__ hb)
{
    const int bid = blockIdx.x, t = threadIdx.x;
    if (bid < 768) {
        const int row = bid, col = t;
        float val;
        if (row < 256) {
            val = Wq[row * 256 + col];
            if (col == 0) b_eff[row] = bq[row];
        } else if (row < 512) {
            const int r = row - 256, hh = r >> 5, e = r & 31;
            // rel_pri / sqrt(32) * log2(e)  -> lets aggregate use exp2 directly
            const float s = rel_pri[hh] * 0.17677669529663687f * 1.4426950408889634f;
            float acc = 0.f;
            for (int d = 0; d < 32; ++d)
                acc += rel_att[hh * 1024 + d * 32 + e] * Wk[(hh * 32 + d) * 256 + col];
            val = acc * s;
            if (col == 0) {
                float b = 0.f;
                for (int d = 0; d < 32; ++d) b += rel_att[hh * 1024 + d * 32 + e] * bk[hh * 32 + d];
                b_eff[row] = b * s;
            }
        } else {
            const int r = row - 512, hh = r >> 5, e = r & 31;
            float acc = 0.f;
            for (int d = 0; d < 32; ++d)
                acc += rel_msg[hh * 1024 + d * 32 + e] * Wv[(hh * 32 + d) * 256 + col];
            val = acc;
            if (col == 0) {
                float b = 0.f;
                for (int d = 0; d < 32; ++d) b += rel_msg[hh * 1024 + d * 32 + e] * bv[hh * 32 + d];
                b_eff[row] = b;
            }
        }
        W_all[row * 256 + col] = f2bf(val);
    } else if (bid < 1024) {
        const int idx = (bid - 768) * 256 + t; // 0..65535
        Wa_bf[idx] = f2bf(Wa[idx]);
    } else {
        const int i = (bid - 1024) * 256 + t;  // one ushort4 per thread
        const int row = i >> 6, c4 = (i & 63) * 4;
        if (row >= MPAD) return;
        ushort4 o;
        if (row < NN) {
            const float4 v = *(const float4*)(h + (size_t)row * 256 + c4);
            o.x = f2bf(v.x); o.y = f2bf(v.y); o.z = f2bf(v.z); o.w = f2bf(v.w);
        } else {
            o = make_ushort4(0, 0, 0, 0);
        }
        *(ushort4*)(hb + (size_t)row * 256 + c4) = o;
    }
}

// ---------------------------------------------------------------- GEMM qkv (C bf16, +bias)
// A[MPAD,256] bf16, B[768,256] bf16 (row = output col), C[MPAD,768] bf16
__global__ __launch_bounds__(256) void gemm_qkv(
    const u16* __restrict__ A, const u16* __restrict__ B,
    const float* __restrict__ bias, u16* __restrict__ C)
{
    __shared__ u16 At[128 * 64];
    __shared__ u16 Bt[128 * 64];
    const int t = threadIdx.x;
    const int wave = t >> 6, lane = t & 63;
    const int row0 = blockIdx.x * 128, col0 = blockIdx.y * 128;
    const int wm = (wave >> 1) * 64, wn = (wave & 1) * 64;
    const int cl = lane & 15, rh = lane >> 4;
    const int srow = t >> 3;           // staging row (within 32-row group), +32 per round
    const int scol = (t & 7) * 8;      // staging col (elements)

    f32x4 acc[4][4] = {};

    for (int k0 = 0; k0 < 256; k0 += 64) {
        __syncthreads();
        #pragma unroll
        for (int r = 0; r < 4; ++r) {
            const int rowT = r * 32 + srow;
            gload_lds16(A + (size_t)(row0 + rowT) * 256 + k0 + scol, &At[(r * 256 + wave * 64) * 8]);
            gload_lds16(B + (size_t)(col0 + rowT) * 256 + k0 + scol, &Bt[(r * 256 + wave * 64) * 8]);
        }
        __syncthreads();
        #pragma unroll
        for (int kk = 0; kk < 64; kk += 32) {
            bf16x8 af[4], bb[4];
            #pragma unroll
            for (int m = 0; m < 4; ++m)
                af[m] = *(const bf16x8*)&At[(wm + 16 * m + cl) * 64 + kk + rh * 8];
            #pragma unroll
            for (int n = 0; n < 4; ++n)
                bb[n] = *(const bf16x8*)&Bt[(wn + 16 * n + cl) * 64 + kk + rh * 8];
            #pragma unroll
            for (int m = 0; m < 4; ++m)
                #pragma unroll
                for (int n = 0; n < 4; ++n)
                    acc[m][n] = __builtin_amdgcn_mfma_f32_16x16x32_bf16(af[m], bb[n], acc[m][n], 0, 0, 0);
        }
    }
    #pragma unroll
    for (int n = 0; n < 4; ++n) {
        const int col = col0 + wn + 16 * n + cl;
        const float bv = bias[col];
        #pragma unroll
        for (int m = 0; m < 4; ++m) {
            const int rowb = row0 + wm + 16 * m + 4 * rh;
            #pragma unroll
            for (int r = 0; r < 4; ++r)
                C[(size_t)(rowb + r) * 768 + col] = f2bf(acc[m][n][r] + bv);
        }
    }
}

// ---------------------------------------------------------------- GEMM out (fp32, residual)
__global__ __launch_bounds__(256) void gemm_out(
    const u16* __restrict__ A, const u16* __restrict__ B,
    const float* __restrict__ bias, const float* __restrict__ hres,
    const float* __restrict__ skip, float* __restrict__ C)
{
    __shared__ u16 At[128 * 64];
    __shared__ u16 Bt[128 * 64];
    const int t = threadIdx.x;
    const int wave = t >> 6, lane = t & 63;
    const int row0 = blockIdx.x * 128, col0 = blockIdx.y * 128;
    const int wm = (wave >> 1) * 64, wn = (wave & 1) * 64;
    const int cl = lane & 15, rh = lane >> 4;
    const int srow = t >> 3, scol = (t & 7) * 8;

    f32x4 acc[4][4] = {};

    for (int k0 = 0; k0 < 256; k0 += 64) {
        __syncthreads();
        #pragma unroll
        for (int r = 0; r < 4; ++r) {
            const int rowT = r * 32 + srow;
            gload_lds16(A + (size_t)(row0 + rowT) * 256 + k0 + scol, &At[(r * 256 + wave * 64) * 8]);
            gload_lds16(B + (size_t)(col0 + rowT) * 256 + k0 + scol, &Bt[(r * 256 + wave * 64) * 8]);
        }
        __syncthreads();
        #pragma unroll
        for (int kk = 0; kk < 64; kk += 32) {
            bf16x8 af[4], bb[4];
            #pragma unroll
            for (int m = 0; m < 4; ++m)
                af[m] = *(const bf16x8*)&At[(wm + 16 * m + cl) * 64 + kk + rh * 8];
            #pragma unroll
            for (int n = 0; n < 4; ++n)
                bb[n] = *(const bf16x8*)&Bt[(wn + 16 * n + cl) * 64 + kk + rh * 8];
            #pragma unroll
            for (int m = 0; m < 4; ++m)
                #pragma unroll
                for (int n = 0; n < 4; ++n)
                    acc[m][n] = __builtin_amdgcn_mfma_f32_16x16x32_bf16(af[m], bb[n], acc[m][n], 0, 0, 0);
        }
    }
    const float alpha = 1.f / (1.f + __expf(-skip[0]));
    const float beta = 1.f - alpha;
    #pragma unroll
    for (int n = 0; n < 4; ++n) {
        const int col = col0 + wn + 16 * n + cl;
        const float bv = bias[col];
        #pragma unroll
        for (int m = 0; m < 4; ++m) {
            const int rowb = row0 + wm + 16 * m + 4 * rh;
            #pragma unroll
            for (int r = 0; r < 4; ++r) {
                const int row = rowb + r;
                if (row < NN)
                    C[(size_t)row * 256 + col] =
                        (acc[m][n][r] + bv) * alpha + hres[(size_t)row * 256 + col] * beta;
            }
        }
    }
}

// ---------------------------------------------------------------- CSR build
__global__ void deg_count(const int* __restrict__ dst, int* __restrict__ deg)
{
    const int e = blockIdx.x * 256 + threadIdx.x;
    if (e < NE) atomicAdd(&deg[dst[e]], 1);
}

// wave-shuffle scan: 3 barriers per 1024-chunk (vs 20 for Hillis-Steele)
__global__ __launch_bounds__(1024) void scan_deg(const int* __restrict__ deg,
                                                 int* __restrict__ off, int* __restrict__ cur)
{
    __shared__ int wsum[16];
    __shared__ int wpre[17];
    const int t = threadIdx.x;
    const int lane = t & 63, wv = t >> 6;
    int carry = 0;
    for (int base = 0; base < NN; base += 1024) {
        const int i = base + t;
        const int v = (i < NN) ? deg[i] : 0;
        int s = v;                      // inclusive intra-wave scan
        #pragma unroll
        for (int o = 1; o < 64; o <<= 1) {
            const int u = __shfl_up(s, o);
            if (lane >= o) s += u;
        }
        if (lane == 63) wsum[wv] = s;
        __syncthreads();
        if (wv == 0) {                  // wave 0 scans the 16 wave-sums
            const int x = (lane < 16) ? wsum[lane] : 0;
            int sx = x;
            #pragma unroll
            for (int o = 1; o < 16; o <<= 1) {
                const int u = __shfl_up(sx, o);
                if (lane >= o) sx += u;
            }
            if (lane < 16) wpre[lane] = sx - x;   // exclusive
            if (lane == 15) wpre[16] = sx;        // chunk total
        }
        __syncthreads();
        const int excl = s - v + wpre[wv] + carry;
        if (i < NN) { off[i] = excl; cur[i] = excl; }
        carry += wpre[16];
        __syncthreads();                // protect wsum/wpre reuse
    }
    if (t == 0) off[NN] = carry;
}

__global__ void scatter_edges(const int* __restrict__ dst, const int* __restrict__ src,
                              int* __restrict__ cur, int* __restrict__ esrc)
{
    const int e = blockIdx.x * 256 + threadIdx.x;
    if (e < NE) {
        const int p = atomicAdd(&cur[dst[e]], 1);
        esrc[p] = src[e];  // store src id directly
    }
}

// ---------------------------------------------------------------- aggregation (1 wave / node)
// half-wave per edge: sub-lane sl (0..31) owns dims [8sl,8sl+8); head = sl>>2.
// edge ids bulk-loaded (one per lane), distributed via __shfl; 4 gathers in flight.
__device__ __forceinline__ void agg_edge(const u16* __restrict__ qkv, int id, bool valid,
                                         const float* qf, int sl, float& z, float* acc)
{
    const u16* base = qkv + (size_t)id * 768 + sl * 8;
    const u16x8 kv = *(const u16x8*)(base + 256);
    const u16x8 vv = *(const u16x8*)(base + 512);
    float s = 0.f;
    #pragma unroll
    for (int j = 0; j < 8; ++j) s += qf[j] * bf2f(kv[j]);
    s += __shfl_xor(s, 1);
    s += __shfl_xor(s, 2);             // 4 sub-lanes = one head's 32 dims
    const float ex = valid ? exp2f(s) : 0.f;   // log2e folded into k
    z += ex;
    #pragma unroll
    for (int j = 0; j < 8; ++j) acc[j] += ex * bf2f(vv[j]);
}

__global__ __launch_bounds__(256) void aggregate(
    const u16* __restrict__ qkv, const int* __restrict__ off,
    const int* __restrict__ esrc, u16* __restrict__ tout)
{
    const int wid = blockIdx.x * 4 + (threadIdx.x >> 6);
    const int lane = threadIdx.x & 63;
    const int half = lane >> 5, sl = lane & 31;
    if (wid >= MPAD) return;
    if (wid >= NN) {                   // zero pad rows for the downstream GEMM
        if (half == 0) *(u16x8*)(tout + (size_t)wid * 256 + sl * 8) = (u16x8)0;
        return;
    }
    const u16x8 qv = *(const u16x8*)(qkv + (size_t)wid * 768 + sl * 8);
    float qf[8];
    #pragma unroll
    for (int j = 0; j < 8; ++j) qf[j] = bf2f(qv[j]);
    float acc[8] = {0.f, 0.f, 0.f, 0.f, 0.f, 0.f, 0.f, 0.f};
    float z = 0.f;
    const int e0 = off[wid], e1 = off[wid + 1];
    for (int c0 = e0; c0 < e1; c0 += 64) {
        const int cnt = min(64, e1 - c0);
        const int jj = c0 + lane;
        const int myid = (jj < e1) ? esrc[jj] : 0;   // all ids for this chunk, in registers
        for (int i = 0; i < cnt; i += 4) {
            const int i0 = i + half;
            const int i1 = i + 2 + half;
            const int id0 = __shfl(myid, i0);
            const int id1 = __shfl(myid, i1);
            agg_edge(qkv, id0, i0 < cnt, qf, sl, z, acc);   // 2 edges (halves)
            agg_edge(qkv, id1, i1 < cnt, qf, sl, z, acc);   // +2 more in flight
        }
    }
    #pragma unroll
    for (int j = 0; j < 8; ++j) acc[j] += __shfl_xor(acc[j], 32);
    z += __shfl_xor(z, 32);
    if (half == 0) {
        const float rz = (z > 0.f) ? 1.f / z : 0.f;
        u16x8 o;
        #pragma unroll
        for (int j = 0; j < 8; ++j) o[j] = f2bf(acc[j] * rz);
        *(u16x8*)(tout + (size_t)wid * 256 + sl * 8) = o;
    }
}

// ---------------------------------------------------------------- launch
extern "C" void kernel_launch(void* const* d_in, const int* in_sizes, int n_in,
                              void* d_out, int out_size, void* d_ws, size_t ws_size,
                              hipStream_t stream)
{
    const float* h   = (const float*)d_in[0];
    const int*   src = (const int*)d_in[1];
    const int*   dst = (const int*)d_in[2];
    const float* Wk  = (const float*)d_in[3];
    const float* bk  = (const float*)d_in[4];
    const float* Wq  = (const float*)d_in[5];
    const float* bq  = (const float*)d_in[6];
    const float* Wv  = (const float*)d_in[7];
    const float* bv  = (const float*)d_in[8];
    const float* Wa  = (const float*)d_in[9];
    const float* ba  = (const float*)d_in[10];
    const float* rel_att = (const float*)d_in[11];
    const float* rel_msg = (const float*)d_in[12];
    const float* rel_pri = (const float*)d_in[13];
    const float* skip    = (const float*)d_in[14];
    float* out = (float*)d_out;

    char* w = (char*)d_ws;
    // ws layout (bytes), ~43.2 MB total:
    u16*   h_bf  = (u16*)(w + 0);           // MPAD*256*2 = 10,289,152
    u16*   W_all = (u16*)(w + 10289152);    // 768*256*2  =    393,216
    float* b_eff = (float*)(w + 10682368);  // 768*4      =      3,072 (+pad)
    u16*   Wa_bf = (u16*)(w + 10685440);    // 256*256*2  =    131,072
    u16*   qkv   = (u16*)(w + 10816512);    // MPAD*768*2 = 30,867,456
    int*   deg   = (int*)(w + 41683968);    // 20000*4    ->     80,128
    int*   off   = (int*)(w + 41764096);    // 20001*4    ->     80,128
    int*   cur   = (int*)(w + 41844224);    //                   80,128
    int*   esrc  = (int*)(w + 41924352);    // NE*4       =  1,280,000
    u16*   t_bf  = h_bf;                    // alias: h_bf dead after gemm_qkv

    (void)hipMemsetAsync(deg, 0, NN * sizeof(int), stream);
    prep_all<<<1024 + MPAD * 64 / 256, 256, 0, stream>>>(
        Wq, bq, Wk, bk, Wv, bv, Wa, rel_att, rel_msg, rel_pri, h,
        W_all, b_eff, Wa_bf, h_bf);
    gemm_qkv<<<dim3(157, 6), 256, 0, stream>>>(h_bf, W_all, b_eff, qkv);
    deg_count<<<NE / 256, 256, 0, stream>>>(dst, deg);
    scan_deg<<<1, 1024, 0, stream>>>(deg, off, cur);
    scatter_edges<<<NE / 256, 256, 0, stream>>>(dst, src, cur, esrc);
    aggregate<<<MPAD / 4, 256, 0, stream>>>(qkv, off, esrc, t_bf);
    gemm_out<<<dim3(157, 2), 256, 0, stream>>>(t_bf, Wa_bf, ba, h, skip, out);
}

// Round 3
// 132.894 us; speedup vs baseline: 1.4870x; 1.2079x over previous
//
#include <hip/hip_runtime.h>
#include <hip/hip_bf16.h>
#include <math.h>

// HGT layer, MI355X. Pipeline:
//  prep_all     : fold rel_att/rel_msg (+rel_pri*log2e/sqrt(dk)) into Wk/Wv -> W_all[768,256] bf16
//                 + cast h fp32->bf16 (pad rows zero) + deg histogram (fused)
//  gemm_qkv     : [MPAD,768] = h_bf @ W_all^T + b_eff; epilogue writes q bf16, k/v OCP-fp8
//  CSR build    : wave-shuffle scan -> scatter (stores src per slot)
//  aggregate    : 1 wave/node, half-wave per edge, fp8 k/v gather (512B/edge), 8 edges in flight
//  gemm_out     : 64x64 tiles; out = (t_bf @ Wa^T + ba)*alpha + h*(1-alpha)

#define NN   20000
#define NE   320000
#define MPAD 20096   // 157*128 = 314*64

typedef unsigned short u16;
typedef unsigned char  u8;
typedef __bf16 bf16x8 __attribute__((ext_vector_type(8)));
typedef u16    u16x8  __attribute__((ext_vector_type(8)));
typedef float  f32x4  __attribute__((ext_vector_type(4)));

__device__ __forceinline__ float bf2f(u16 x) {
    union { float f; unsigned u; } c; c.u = ((unsigned)x) << 16; return c.f;
}
__device__ __forceinline__ u16 f2bf(float f) {
    union { float f; unsigned u; } c; c.f = f;
    unsigned r = c.u + 0x7fffu + ((c.u >> 16) & 1u);
    return (u16)(r >> 16);
}

#if __has_builtin(__builtin_amdgcn_cvt_pk_fp8_f32) && __has_builtin(__builtin_amdgcn_cvt_pk_f32_fp8)
#define HWFP8 1
#else
#define HWFP8 0
#endif

__device__ __forceinline__ u8 f2fp8(float x) {
#if HWFP8
    return (u8)(__builtin_amdgcn_cvt_pk_fp8_f32(x, x, 0, false) & 0xff);
#else
    if (x != x) return 0x7f;
    unsigned sg = (x < 0.f) ? 0x80u : 0u;
    float a = fabsf(x); if (a > 448.f) a = 448.f;
    if (a < 0.015625f) {                       // denormal: step 2^-9
        int m = (int)rintf(a * 512.f);
        if (m > 7) return (u8)(sg | 0x08);
        return (u8)(sg | m);
    }
    int e; (void)frexpf(a, &e);                // a = fr*2^e, fr in [0.5,1)
    int p = e - 1;
    float mant = a * exp2f((float)(-p));       // [1,2)
    int m = (int)rintf((mant - 1.f) * 8.f);
    int ef = p + 7;
    if (m == 8) { m = 0; ef++; }
    if (ef > 15) { ef = 15; m = 6; }
    return (u8)(sg | (ef << 3) | m);
#endif
}

__device__ __forceinline__ void fp8x4_dec(unsigned w, float* o) {
#if HWFP8
    auto lo = __builtin_amdgcn_cvt_pk_f32_fp8(w, false);
    auto hi = __builtin_amdgcn_cvt_pk_f32_fp8(w, true);
    o[0] = lo[0]; o[1] = lo[1]; o[2] = hi[0]; o[3] = hi[1];
#else
    #pragma unroll
    for (int j = 0; j < 4; ++j) {
        u8 b = (w >> (8 * j)) & 0xff;
        unsigned e = (b >> 3) & 15, m = b & 7;
        float v;
        if (e) { union { unsigned u; float f; } c; c.u = ((e + 120) << 23) | (m << 20); v = c.f; }
        else v = (float)m * 0.001953125f;
        o[j] = (b & 0x80) ? -v : v;
    }
#endif
}

__device__ __forceinline__ float fast_exp2(float x) {
#if __has_builtin(__builtin_amdgcn_exp2f)
    return __builtin_amdgcn_exp2f(x);
#else
    return exp2f(x);
#endif
}

__device__ __forceinline__ void gload_lds16(const void* g, void* l) {
    __builtin_amdgcn_global_load_lds(
        (const __attribute__((address_space(1))) unsigned*)g,
        (__attribute__((address_space(3))) unsigned*)l, 16, 0, 0);
}

// ---------------------------------------------------------------- prep (weights + h cast + deg)
// blocks 0..767    : row of W_all (0-255 Wq, 256-511 rel_att*Wk*scale, 512-767 rel_msg*Wv)
// blocks 768..1023 : cast Wa -> bf16
// blocks 1024..6047: cast h -> bf16, pad rows zeroed
// blocks 6048..7297: deg histogram
__global__ void prep_all(const float* __restrict__ Wq, const float* __restrict__ bq,
                         const float* __restrict__ Wk, const float* __restrict__ bk,
                         const float* __restrict__ Wv, const float* __restrict__ bv,
                         const float* __restrict__ Wa,
                         const float* __restrict__ rel_att, const float* __restrict__ rel_msg,
                         const float* __restrict__ rel_pri,
                         const float* __restrict__ h, const int* __restrict__ dst,
                         u16* __restrict__ W_all, float* __restrict__ b_eff,
                         u16* __restrict__ Wa_bf, u16* __restrict__ hb, int* __restrict__ deg)
{
    const int bid = blockIdx.x, t = threadIdx.x;
    if (bid < 768) {
        const int row = bid, col = t;
        float val;
        if (row < 256) {
            val = Wq[row * 256 + col];
            if (col == 0) b_eff[row] = bq[row];
        } else if (row < 512) {
            const int r = row - 256, hh = r >> 5, e = r & 31;
            // rel_pri / sqrt(32) * log2(e) -> aggregate uses exp2 directly
            const float s = rel_pri[hh] * 0.17677669529663687f * 1.4426950408889634f;
            float acc = 0.f;
            for (int d = 0; d < 32; ++d)
                acc += rel_att[hh * 1024 + d * 32 + e] * Wk[(hh * 32 + d) * 256 + col];
            val = acc * s;
            if (col == 0) {
                float b = 0.f;
                for (int d = 0; d < 32; ++d) b += rel_att[hh * 1024 + d * 32 + e] * bk[hh * 32 + d];
                b_eff[row] = b * s;
            }
        } else {
            const int r = row - 512, hh = r >> 5, e = r & 31;
            float acc = 0.f;
            for (int d = 0; d < 32; ++d)
                acc += rel_msg[hh * 1024 + d * 32 + e] * Wv[(hh * 32 + d) * 256 + col];
            val = acc;
            if (col == 0) {
                float b = 0.f;
                for (int d = 0; d < 32; ++d) b += rel_msg[hh * 1024 + d * 32 + e] * bv[hh * 32 + d];
                b_eff[row] = b;
            }
        }
        W_all[row * 256 + col] = f2bf(val);
    } else if (bid < 1024) {
        const int idx = (bid - 768) * 256 + t;
        Wa_bf[idx] = f2bf(Wa[idx]);
    } else if (bid < 6048) {
        const int i = (bid - 1024) * 256 + t;  // one ushort4 per thread
        const int row = i >> 6, c4 = (i & 63) * 4;
        if (row >= MPAD) return;
        ushort4 o;
        if (row < NN) {
            const float4 v = *(const float4*)(h + (size_t)row * 256 + c4);
            o.x = f2bf(v.x); o.y = f2bf(v.y); o.z = f2bf(v.z); o.w = f2bf(v.w);
        } else {
            o = make_ushort4(0, 0, 0, 0);
        }
        *(ushort4*)(hb + (size_t)row * 256 + c4) = o;
    } else {
        const int e = (bid - 6048) * 256 + t;
        if (e < NE) atomicAdd(&deg[dst[e]], 1);
    }
}

// ---------------------------------------------------------------- GEMM qkv
// A[MPAD,256] bf16, B[768,256] bf16 (row = out col). Epilogue: q bf16, k/v fp8.
__global__ __launch_bounds__(256) void gemm_qkv(
    const u16* __restrict__ A, const u16* __restrict__ B,
    const float* __restrict__ bias, u16* __restrict__ qb, u8* __restrict__ kv8)
{
    __shared__ u16 At[128 * 64];
    __shared__ u16 Bt[128 * 64];
    const int t = threadIdx.x;
    const int wave = t >> 6, lane = t & 63;
    const int row0 = blockIdx.x * 128, col0 = blockIdx.y * 128;
    const int wm = (wave >> 1) * 64, wn = (wave & 1) * 64;
    const int cl = lane & 15, rh = lane >> 4;
    const int srow = t >> 3, scol = (t & 7) * 8;

    f32x4 acc[4][4] = {};

    for (int k0 = 0; k0 < 256; k0 += 64) {
        __syncthreads();
        #pragma unroll
        for (int r = 0; r < 4; ++r) {
            const int rowT = r * 32 + srow;
            gload_lds16(A + (size_t)(row0 + rowT) * 256 + k0 + scol, &At[(r * 256 + wave * 64) * 8]);
            gload_lds16(B + (size_t)(col0 + rowT) * 256 + k0 + scol, &Bt[(r * 256 + wave * 64) * 8]);
        }
        __syncthreads();
        #pragma unroll
        for (int kk = 0; kk < 64; kk += 32) {
            bf16x8 af[4], bb[4];
            #pragma unroll
            for (int m = 0; m < 4; ++m)
                af[m] = *(const bf16x8*)&At[(wm + 16 * m + cl) * 64 + kk + rh * 8];
            #pragma unroll
            for (int n = 0; n < 4; ++n)
                bb[n] = *(const bf16x8*)&Bt[(wn + 16 * n + cl) * 64 + kk + rh * 8];
            #pragma unroll
            for (int m = 0; m < 4; ++m)
                #pragma unroll
                for (int n = 0; n < 4; ++n)
                    acc[m][n] = __builtin_amdgcn_mfma_f32_16x16x32_bf16(af[m], bb[n], acc[m][n], 0, 0, 0);
        }
    }
    #pragma unroll
    for (int n = 0; n < 4; ++n) {
        const int col = col0 + wn + 16 * n + cl;
        const float bv = bias[col];
        #pragma unroll
        for (int m = 0; m < 4; ++m) {
            const int rowb = row0 + wm + 16 * m + 4 * rh;
            #pragma unroll
            for (int r = 0; r < 4; ++r) {
                const float val = acc[m][n][r] + bv;
                const size_t row = (size_t)(rowb + r);
                if (col < 256)      qb[row * 256 + col] = f2bf(val);
                else if (col < 512) kv8[row * 512 + (col - 256)] = f2fp8(val);
                else                kv8[row * 512 + 256 + (col - 512)] = f2fp8(val);
            }
        }
    }
}

// ---------------------------------------------------------------- GEMM out (64x64 tiles, fp32 out)
__global__ __launch_bounds__(256) void gemm_out(
    const u16* __restrict__ A, const u16* __restrict__ B,
    const float* __restrict__ bias, const float* __restrict__ hres,
    const float* __restrict__ skip, float* __restrict__ C)
{
    __shared__ u16 At[64 * 64];
    __shared__ u16 Bt[64 * 64];
    const int t = threadIdx.x;
    const int wave = t >> 6, lane = t & 63;
    const int row0 = blockIdx.x * 64, col0 = blockIdx.y * 64;
    const int wm = (wave >> 1) * 32, wn = (wave & 1) * 32;
    const int cl = lane & 15, rh = lane >> 4;
    const int srow = t >> 3, scol = (t & 7) * 8;

    f32x4 acc[2][2] = {};

    for (int k0 = 0; k0 < 256; k0 += 64) {
        __syncthreads();
        #pragma unroll
        for (int r = 0; r < 2; ++r) {
            const int rowT = r * 32 + srow;
            gload_lds16(A + (size_t)(row0 + rowT) * 256 + k0 + scol, &At[(r * 2048 + wave * 512)]);
            gload_lds16(B + (size_t)(col0 + rowT) * 256 + k0 + scol, &Bt[(r * 2048 + wave * 512)]);
        }
        __syncthreads();
        #pragma unroll
        for (int kk = 0; kk < 64; kk += 32) {
            bf16x8 af[2], bb[2];
            #pragma unroll
            for (int m = 0; m < 2; ++m)
                af[m] = *(const bf16x8*)&At[(wm + 16 * m + cl) * 64 + kk + rh * 8];
            #pragma unroll
            for (int n = 0; n < 2; ++n)
                bb[n] = *(const bf16x8*)&Bt[(wn + 16 * n + cl) * 64 + kk + rh * 8];
            #pragma unroll
            for (int m = 0; m < 2; ++m)
                #pragma unroll
                for (int n = 0; n < 2; ++n)
                    acc[m][n] = __builtin_amdgcn_mfma_f32_16x16x32_bf16(af[m], bb[n], acc[m][n], 0, 0, 0);
        }
    }
    const float alpha = 1.f / (1.f + __expf(-skip[0]));
    const float beta = 1.f - alpha;
    #pragma unroll
    for (int n = 0; n < 2; ++n) {
        const int col = col0 + wn + 16 * n + cl;
        const float bv = bias[col];
        #pragma unroll
        for (int m = 0; m < 2; ++m) {
            const int rowb = row0 + wm + 16 * m + 4 * rh;
            #pragma unroll
            for (int r = 0; r < 4; ++r) {
                const int row = rowb + r;
                if (row < NN)
                    C[(size_t)row * 256 + col] =
                        (acc[m][n][r] + bv) * alpha + hres[(size_t)row * 256 + col] * beta;
            }
        }
    }
}

// ---------------------------------------------------------------- CSR build
__global__ __launch_bounds__(1024) void scan_deg(const int* __restrict__ deg,
                                                 int* __restrict__ off, int* __restrict__ cur)
{
    __shared__ int wsum[16];
    __shared__ int wpre[17];
    const int t = threadIdx.x;
    const int lane = t & 63, wv = t >> 6;
    int carry = 0;
    for (int base = 0; base < NN; base += 1024) {
        const int i = base + t;
        const int v = (i < NN) ? deg[i] : 0;
        int s = v;
        #pragma unroll
        for (int o = 1; o < 64; o <<= 1) {
            const int u = __shfl_up(s, o);
            if (lane >= o) s += u;
        }
        if (lane == 63) wsum[wv] = s;
        __syncthreads();
        if (wv == 0) {
            const int x = (lane < 16) ? wsum[lane] : 0;
            int sx = x;
            #pragma unroll
            for (int o = 1; o < 16; o <<= 1) {
                const int u = __shfl_up(sx, o);
                if (lane >= o) sx += u;
            }
            if (lane < 16) wpre[lane] = sx - x;
            if (lane == 15) wpre[16] = sx;
        }
        __syncthreads();
        const int excl = s - v + wpre[wv] + carry;
        if (i < NN) { off[i] = excl; cur[i] = excl; }
        carry += wpre[16];
        __syncthreads();
    }
    if (t == 0) off[NN] = carry;
}

__global__ void scatter_edges(const int* __restrict__ dst, const int* __restrict__ src,
                              int* __restrict__ cur, int* __restrict__ esrc)
{
    const int e = blockIdx.x * 256 + threadIdx.x;
    if (e < NE) {
        const int p = atomicAdd(&cur[dst[e]], 1);
        esrc[p] = src[e];
    }
}

// ---------------------------------------------------------------- aggregation (1 wave / node)
// half-wave per edge: sub-lane sl (0..31) owns dims [8sl,8sl+8); head = sl>>2.
__device__ __forceinline__ void agg_edge(const u8* __restrict__ kv8, int id, bool valid,
                                         const float* qf, int sl, float& z, float* acc)
{
    const u8* base = kv8 + (size_t)id * 512 + sl * 8;
    const uint2 kw = *(const uint2*)base;          // 8 fp8 k
    const uint2 vw = *(const uint2*)(base + 256);  // 8 fp8 v
    float kf[8], vf[8];
    fp8x4_dec(kw.x, kf); fp8x4_dec(kw.y, kf + 4);
    float s = 0.f;
    #pragma unroll
    for (int j = 0; j < 8; ++j) s += qf[j] * kf[j];
    s += __shfl_xor(s, 1);
    s += __shfl_xor(s, 2);             // 4 sub-lanes = one head's 32 dims
    const float ex = valid ? fast_exp2(s) : 0.f;   // log2e folded into k
    z += ex;
    fp8x4_dec(vw.x, vf); fp8x4_dec(vw.y, vf + 4);
    #pragma unroll
    for (int j = 0; j < 8; ++j) acc[j] += ex * vf[j];
}

__global__ __launch_bounds__(256) void aggregate(
    const u16* __restrict__ qb, const u8* __restrict__ kv8, const int* __restrict__ off,
    const int* __restrict__ esrc, u16* __restrict__ tout)
{
    const int wid = blockIdx.x * 4 + (threadIdx.x >> 6);
    const int lane = threadIdx.x & 63;
    const int half = lane >> 5, sl = lane & 31;
    if (wid >= MPAD) return;
    if (wid >= NN) {                   // zero pad rows for the downstream GEMM
        if (half == 0) *(u16x8*)(tout + (size_t)wid * 256 + sl * 8) = (u16x8)0;
        return;
    }
    const u16x8 qv = *(const u16x8*)(qb + (size_t)wid * 256 + sl * 8);
    float qf[8];
    #pragma unroll
    for (int j = 0; j < 8; ++j) qf[j] = bf2f(qv[j]);
    float acc[8] = {0.f, 0.f, 0.f, 0.f, 0.f, 0.f, 0.f, 0.f};
    float z = 0.f;
    const int e0 = off[wid], e1 = off[wid + 1];
    for (int c0 = e0; c0 < e1; c0 += 64) {
        const int cnt = min(64, e1 - c0);
        const int jj = c0 + lane;
        const int myid = (jj < e1) ? esrc[jj] : 0;   // chunk ids in registers
        for (int i = 0; i < cnt; i += 8) {           // 8 edges / iteration (4 per half)
            const int i0 = i + half,     i1 = i + 2 + half;
            const int i2 = i + 4 + half, i3 = i + 6 + half;
            const int id0 = __shfl(myid, i0), id1 = __shfl(myid, i1);
            const int id2 = __shfl(myid, i2), id3 = __shfl(myid, i3);
            agg_edge(kv8, id0, i0 < cnt, qf, sl, z, acc);
            agg_edge(kv8, id1, i1 < cnt, qf, sl, z, acc);
            agg_edge(kv8, id2, i2 < cnt, qf, sl, z, acc);
            agg_edge(kv8, id3, i3 < cnt, qf, sl, z, acc);
        }
    }
    #pragma unroll
    for (int j = 0; j < 8; ++j) acc[j] += __shfl_xor(acc[j], 32);
    z += __shfl_xor(z, 32);
    if (half == 0) {
        const float rz = (z > 0.f) ? 1.f / z : 0.f;
        u16x8 o;
        #pragma unroll
        for (int j = 0; j < 8; ++j) o[j] = f2bf(acc[j] * rz);
        *(u16x8*)(tout + (size_t)wid * 256 + sl * 8) = o;
    }
}

// ---------------------------------------------------------------- launch
extern "C" void kernel_launch(void* const* d_in, const int* in_sizes, int n_in,
                              void* d_out, int out_size, void* d_ws, size_t ws_size,
                              hipStream_t stream)
{
    const float* h   = (const float*)d_in[0];
    const int*   src = (const int*)d_in[1];
    const int*   dst = (const int*)d_in[2];
    const float* Wk  = (const float*)d_in[3];
    const float* bk  = (const float*)d_in[4];
    const float* Wq  = (const float*)d_in[5];
    const float* bq  = (const float*)d_in[6];
    const float* Wv  = (const float*)d_in[7];
    const float* bv  = (const float*)d_in[8];
    const float* Wa  = (const float*)d_in[9];
    const float* ba  = (const float*)d_in[10];
    const float* rel_att = (const float*)d_in[11];
    const float* rel_msg = (const float*)d_in[12];
    const float* rel_pri = (const float*)d_in[13];
    const float* skip    = (const float*)d_in[14];
    float* out = (float*)d_out;

    char* w = (char*)d_ws;
    // ws layout (bytes), ~33 MB total:
    u16* h_bf  = (u16*)(w + 0);           // MPAD*256*2 = 10,289,152
    u16* W_all = (u16*)(w + 10289152);    // 768*256*2  =    393,216
    float* b_eff = (float*)(w + 10682368);// 768*4 (+pad)
    u16* Wa_bf = (u16*)(w + 10685440);    // 256*256*2  =    131,072
    u16* qb    = (u16*)(w + 10816512);    // MPAD*256*2 = 10,289,152
    u8*  kv8   = (u8*)(w + 21105664);     // MPAD*512   = 10,289,152
    int* deg   = (int*)(w + 31394816);    // 20000*4 (+pad)
    int* off   = (int*)(w + 31474944);    // 20001*4 (+pad)
    int* cur   = (int*)(w + 31555072);
    int* esrc  = (int*)(w + 31635200);    // NE*4 = 1,280,000
    u16* t_bf  = h_bf;                    // alias: h_bf dead after gemm_qkv

    (void)hipMemsetAsync(deg, 0, NN * sizeof(int), stream);
    prep_all<<<7298, 256, 0, stream>>>(Wq, bq, Wk, bk, Wv, bv, Wa,
                                       rel_att, rel_msg, rel_pri, h, dst,
                                       W_all, b_eff, Wa_bf, h_bf, deg);
    gemm_qkv<<<dim3(157, 6), 256, 0, stream>>>(h_bf, W_all, b_eff, qb, kv8);
    scan_deg<<<1, 1024, 0, stream>>>(deg, off, cur);
    scatter_edges<<<NE / 256, 256, 0, stream>>>(dst, src, cur, esrc);
    aggregate<<<MPAD / 4, 256, 0, stream>>>(qb, kv8, off, esrc, t_bf);
    gemm_out<<<dim3(314, 4), 256, 0, stream>>>(t_bf, Wa_bf, ba, h, skip, out);
}

// Round 4
// 132.443 us; speedup vs baseline: 1.4921x; 1.0034x over previous
//
#include <hip/hip_runtime.h>
#include <hip/hip_bf16.h>
#include <math.h>

// HGT layer, MI355X. Pipeline:
//  zero_deg     : zero the degree array (replaces hipMemsetAsync -- the rocclr fill
//                 kernel cost 41us/replay for an 80KB clear)
//  prep_all     : fold rel_att/rel_msg (+rel_pri*log2e/sqrt(dk)) into Wk/Wv -> W_all[768,256] bf16
//                 + cast h fp32->bf16 (pad rows zero) + deg histogram (fused)
//  gemm_qkv     : [MPAD,768] = h_bf @ W_all^T + b_eff; epilogue writes q bf16, k/v OCP-fp8
//  CSR build    : wave-shuffle scan -> scatter (stores src per slot)
//  aggregate    : 1 wave/node, half-wave per edge, fp8 k/v gather (512B/edge), 8 edges in flight
//  gemm_out     : 64x64 tiles; out = (t_bf @ Wa^T + ba)*alpha + h*(1-alpha)

#define NN   20000
#define NE   320000
#define MPAD 20096   // 157*128 = 314*64

typedef unsigned short u16;
typedef unsigned char  u8;
typedef __bf16 bf16x8 __attribute__((ext_vector_type(8)));
typedef u16    u16x8  __attribute__((ext_vector_type(8)));
typedef float  f32x4  __attribute__((ext_vector_type(4)));

__device__ __forceinline__ float bf2f(u16 x) {
    union { float f; unsigned u; } c; c.u = ((unsigned)x) << 16; return c.f;
}
__device__ __forceinline__ u16 f2bf(float f) {
    union { float f; unsigned u; } c; c.f = f;
    unsigned r = c.u + 0x7fffu + ((c.u >> 16) & 1u);
    return (u16)(r >> 16);
}

#if __has_builtin(__builtin_amdgcn_cvt_pk_fp8_f32) && __has_builtin(__builtin_amdgcn_cvt_pk_f32_fp8)
#define HWFP8 1
#else
#define HWFP8 0
#endif

__device__ __forceinline__ u8 f2fp8(float x) {
#if HWFP8
    return (u8)(__builtin_amdgcn_cvt_pk_fp8_f32(x, x, 0, false) & 0xff);
#else
    if (x != x) return 0x7f;
    unsigned sg = (x < 0.f) ? 0x80u : 0u;
    float a = fabsf(x); if (a > 448.f) a = 448.f;
    if (a < 0.015625f) {
        int m = (int)rintf(a * 512.f);
        if (m > 7) return (u8)(sg | 0x08);
        return (u8)(sg | m);
    }
    int e; (void)frexpf(a, &e);
    int p = e - 1;
    float mant = a * exp2f((float)(-p));
    int m = (int)rintf((mant - 1.f) * 8.f);
    int ef = p + 7;
    if (m == 8) { m = 0; ef++; }
    if (ef > 15) { ef = 15; m = 6; }
    return (u8)(sg | (ef << 3) | m);
#endif
}

__device__ __forceinline__ void fp8x4_dec(unsigned w, float* o) {
#if HWFP8
    auto lo = __builtin_amdgcn_cvt_pk_f32_fp8(w, false);
    auto hi = __builtin_amdgcn_cvt_pk_f32_fp8(w, true);
    o[0] = lo[0]; o[1] = lo[1]; o[2] = hi[0]; o[3] = hi[1];
#else
    #pragma unroll
    for (int j = 0; j < 4; ++j) {
        u8 b = (w >> (8 * j)) & 0xff;
        unsigned e = (b >> 3) & 15, m = b & 7;
        float v;
        if (e) { union { unsigned u; float f; } c; c.u = ((e + 120) << 23) | (m << 20); v = c.f; }
        else v = (float)m * 0.001953125f;
        o[j] = (b & 0x80) ? -v : v;
    }
#endif
}

__device__ __forceinline__ float fast_exp2(float x) {
#if __has_builtin(__builtin_amdgcn_exp2f)
    return __builtin_amdgcn_exp2f(x);
#else
    return exp2f(x);
#endif
}

__device__ __forceinline__ void gload_lds16(const void* g, void* l) {
    __builtin_amdgcn_global_load_lds(
        (const __attribute__((address_space(1))) unsigned*)g,
        (__attribute__((address_space(3))) unsigned*)l, 16, 0, 0);
}

// ---------------------------------------------------------------- zero deg (80 KB)
__global__ void zero_deg(int* __restrict__ deg)
{
    const int i = blockIdx.x * 256 + threadIdx.x;   // int4 per thread, 20 blocks
    if (i * 4 < NN + 64) *(int4*)(deg + i * 4) = make_int4(0, 0, 0, 0);
}

// ---------------------------------------------------------------- prep (weights + h cast + deg)
// blocks 0..767    : row of W_all (0-255 Wq, 256-511 rel_att*Wk*scale, 512-767 rel_msg*Wv)
// blocks 768..1023 : cast Wa -> bf16
// blocks 1024..6047: cast h -> bf16, pad rows zeroed
// blocks 6048..7297: deg histogram
__global__ void prep_all(const float* __restrict__ Wq, const float* __restrict__ bq,
                         const float* __restrict__ Wk, const float* __restrict__ bk,
                         const float* __restrict__ Wv, const float* __restrict__ bv,
                         const float* __restrict__ Wa,
                         const float* __restrict__ rel_att, const float* __restrict__ rel_msg,
                         const float* __restrict__ rel_pri,
                         const float* __restrict__ h, const int* __restrict__ dst,
                         u16* __restrict__ W_all, float* __restrict__ b_eff,
                         u16* __restrict__ Wa_bf, u16* __restrict__ hb, int* __restrict__ deg)
{
    const int bid = blockIdx.x, t = threadIdx.x;
    if (bid < 768) {
        const int row = bid, col = t;
        float val;
        if (row < 256) {
            val = Wq[row * 256 + col];
            if (col == 0) b_eff[row] = bq[row];
        } else if (row < 512) {
            const int r = row - 256, hh = r >> 5, e = r & 31;
            // rel_pri / sqrt(32) * log2(e) -> aggregate uses exp2 directly
            const float s = rel_pri[hh] * 0.17677669529663687f * 1.4426950408889634f;
            float acc = 0.f;
            for (int d = 0; d < 32; ++d)
                acc += rel_att[hh * 1024 + d * 32 + e] * Wk[(hh * 32 + d) * 256 + col];
            val = acc * s;
            if (col == 0) {
                float b = 0.f;
                for (int d = 0; d < 32; ++d) b += rel_att[hh * 1024 + d * 32 + e] * bk[hh * 32 + d];
                b_eff[row] = b * s;
            }
        } else {
            const int r = row - 512, hh = r >> 5, e = r & 31;
            float acc = 0.f;
            for (int d = 0; d < 32; ++d)
                acc += rel_msg[hh * 1024 + d * 32 + e] * Wv[(hh * 32 + d) * 256 + col];
            val = acc;
            if (col == 0) {
                float b = 0.f;
                for (int d = 0; d < 32; ++d) b += rel_msg[hh * 1024 + d * 32 + e] * bv[hh * 32 + d];
                b_eff[row] = b;
            }
        }
        W_all[row * 256 + col] = f2bf(val);
    } else if (bid < 1024) {
        const int idx = (bid - 768) * 256 + t;
        Wa_bf[idx] = f2bf(Wa[idx]);
    } else if (bid < 6048) {
        const int i = (bid - 1024) * 256 + t;  // one ushort4 per thread
        const int row = i >> 6, c4 = (i & 63) * 4;
        if (row >= MPAD) return;
        ushort4 o;
        if (row < NN) {
            const float4 v = *(const float4*)(h + (size_t)row * 256 + c4);
            o.x = f2bf(v.x); o.y = f2bf(v.y); o.z = f2bf(v.z); o.w = f2bf(v.w);
        } else {
            o = make_ushort4(0, 0, 0, 0);
        }
        *(ushort4*)(hb + (size_t)row * 256 + c4) = o;
    } else {
        const int e = (bid - 6048) * 256 + t;
        if (e < NE) atomicAdd(&deg[dst[e]], 1);
    }
}

// ---------------------------------------------------------------- GEMM qkv
// A[MPAD,256] bf16, B[768,256] bf16 (row = out col). Epilogue: q bf16, k/v fp8.
__global__ __launch_bounds__(256) void gemm_qkv(
    const u16* __restrict__ A, const u16* __restrict__ B,
    const float* __restrict__ bias, u16* __restrict__ qb, u8* __restrict__ kv8)
{
    __shared__ u16 At[128 * 64];
    __shared__ u16 Bt[128 * 64];
    const int t = threadIdx.x;
    const int wave = t >> 6, lane = t & 63;
    const int row0 = blockIdx.x * 128, col0 = blockIdx.y * 128;
    const int wm = (wave >> 1) * 64, wn = (wave & 1) * 64;
    const int cl = lane & 15, rh = lane >> 4;
    const int srow = t >> 3, scol = (t & 7) * 8;

    f32x4 acc[4][4] = {};

    for (int k0 = 0; k0 < 256; k0 += 64) {
        __syncthreads();
        #pragma unroll
        for (int r = 0; r < 4; ++r) {
            const int rowT = r * 32 + srow;
            gload_lds16(A + (size_t)(row0 + rowT) * 256 + k0 + scol, &At[(r * 256 + wave * 64) * 8]);
            gload_lds16(B + (size_t)(col0 + rowT) * 256 + k0 + scol, &Bt[(r * 256 + wave * 64) * 8]);
        }
        __syncthreads();
        #pragma unroll
        for (int kk = 0; kk < 64; kk += 32) {
            bf16x8 af[4], bb[4];
            #pragma unroll
            for (int m = 0; m < 4; ++m)
                af[m] = *(const bf16x8*)&At[(wm + 16 * m + cl) * 64 + kk + rh * 8];
            #pragma unroll
            for (int n = 0; n < 4; ++n)
                bb[n] = *(const bf16x8*)&Bt[(wn + 16 * n + cl) * 64 + kk + rh * 8];
            #pragma unroll
            for (int m = 0; m < 4; ++m)
                #pragma unroll
                for (int n = 0; n < 4; ++n)
                    acc[m][n] = __builtin_amdgcn_mfma_f32_16x16x32_bf16(af[m], bb[n], acc[m][n], 0, 0, 0);
        }
    }
    #pragma unroll
    for (int n = 0; n < 4; ++n) {
        const int col = col0 + wn + 16 * n + cl;
        const float bv = bias[col];
        #pragma unroll
        for (int m = 0; m < 4; ++m) {
            const int rowb = row0 + wm + 16 * m + 4 * rh;
            #pragma unroll
            for (int r = 0; r < 4; ++r) {
                const float val = acc[m][n][r] + bv;
                const size_t row = (size_t)(rowb + r);
                if (col < 256)      qb[row * 256 + col] = f2bf(val);
                else if (col < 512) kv8[row * 512 + (col - 256)] = f2fp8(val);
                else                kv8[row * 512 + 256 + (col - 512)] = f2fp8(val);
            }
        }
    }
}

// ---------------------------------------------------------------- GEMM out (64x64 tiles, fp32 out)
__global__ __launch_bounds__(256) void gemm_out(
    const u16* __restrict__ A, const u16* __restrict__ B,
    const float* __restrict__ bias, const float* __restrict__ hres,
    const float* __restrict__ skip, float* __restrict__ C)
{
    __shared__ u16 At[64 * 64];
    __shared__ u16 Bt[64 * 64];
    const int t = threadIdx.x;
    const int wave = t >> 6, lane = t & 63;
    const int row0 = blockIdx.x * 64, col0 = blockIdx.y * 64;
    const int wm = (wave >> 1) * 32, wn = (wave & 1) * 32;
    const int cl = lane & 15, rh = lane >> 4;
    const int srow = t >> 3, scol = (t & 7) * 8;

    f32x4 acc[2][2] = {};

    for (int k0 = 0; k0 < 256; k0 += 64) {
        __syncthreads();
        #pragma unroll
        for (int r = 0; r < 2; ++r) {
            const int rowT = r * 32 + srow;
            gload_lds16(A + (size_t)(row0 + rowT) * 256 + k0 + scol, &At[(r * 2048 + wave * 512)]);
            gload_lds16(B + (size_t)(col0 + rowT) * 256 + k0 + scol, &Bt[(r * 2048 + wave * 512)]);
        }
        __syncthreads();
        #pragma unroll
        for (int kk = 0; kk < 64; kk += 32) {
            bf16x8 af[2], bb[2];
            #pragma unroll
            for (int m = 0; m < 2; ++m)
                af[m] = *(const bf16x8*)&At[(wm + 16 * m + cl) * 64 + kk + rh * 8];
            #pragma unroll
            for (int n = 0; n < 2; ++n)
                bb[n] = *(const bf16x8*)&Bt[(wn + 16 * n + cl) * 64 + kk + rh * 8];
            #pragma unroll
            for (int m = 0; m < 2; ++m)
                #pragma unroll
                for (int n = 0; n < 2; ++n)
                    acc[m][n] = __builtin_amdgcn_mfma_f32_16x16x32_bf16(af[m], bb[n], acc[m][n], 0, 0, 0);
        }
    }
    const float alpha = 1.f / (1.f + __expf(-skip[0]));
    const float beta = 1.f - alpha;
    #pragma unroll
    for (int n = 0; n < 2; ++n) {
        const int col = col0 + wn + 16 * n + cl;
        const float bv = bias[col];
        #pragma unroll
        for (int m = 0; m < 2; ++m) {
            const int rowb = row0 + wm + 16 * m + 4 * rh;
            #pragma unroll
            for (int r = 0; r < 4; ++r) {
                const int row = rowb + r;
                if (row < NN)
                    C[(size_t)row * 256 + col] =
                        (acc[m][n][r] + bv) * alpha + hres[(size_t)row * 256 + col] * beta;
            }
        }
    }
}

// ---------------------------------------------------------------- CSR build
__global__ __launch_bounds__(1024) void scan_deg(const int* __restrict__ deg,
                                                 int* __restrict__ off, int* __restrict__ cur)
{
    __shared__ int wsum[16];
    __shared__ int wpre[17];
    const int t = threadIdx.x;
    const int lane = t & 63, wv = t >> 6;
    int carry = 0;
    for (int base = 0; base < NN; base += 1024) {
        const int i = base + t;
        const int v = (i < NN) ? deg[i] : 0;
        int s = v;
        #pragma unroll
        for (int o = 1; o < 64; o <<= 1) {
            const int u = __shfl_up(s, o);
            if (lane >= o) s += u;
        }
        if (lane == 63) wsum[wv] = s;
        __syncthreads();
        if (wv == 0) {
            const int x = (lane < 16) ? wsum[lane] : 0;
            int sx = x;
            #pragma unroll
            for (int o = 1; o < 16; o <<= 1) {
                const int u = __shfl_up(sx, o);
                if (lane >= o) sx += u;
            }
            if (lane < 16) wpre[lane] = sx - x;
            if (lane == 15) wpre[16] = sx;
        }
        __syncthreads();
        const int excl = s - v + wpre[wv] + carry;
        if (i < NN) { off[i] = excl; cur[i] = excl; }
        carry += wpre[16];
        __syncthreads();
    }
    if (t == 0) off[NN] = carry;
}

__global__ void scatter_edges(const int* __restrict__ dst, const int* __restrict__ src,
                              int* __restrict__ cur, int* __restrict__ esrc)
{
    const int e = blockIdx.x * 256 + threadIdx.x;
    if (e < NE) {
        const int p = atomicAdd(&cur[dst[e]], 1);
        esrc[p] = src[e];
    }
}

// ---------------------------------------------------------------- aggregation (1 wave / node)
// half-wave per edge: sub-lane sl (0..31) owns dims [8sl,8sl+8); head = sl>>2.
__device__ __forceinline__ void agg_edge(const u8* __restrict__ kv8, int id, bool valid,
                                         const float* qf, int sl, float& z, float* acc)
{
    const u8* base = kv8 + (size_t)id * 512 + sl * 8;
    const uint2 kw = *(const uint2*)base;          // 8 fp8 k
    const uint2 vw = *(const uint2*)(base + 256);  // 8 fp8 v
    float kf[8], vf[8];
    fp8x4_dec(kw.x, kf); fp8x4_dec(kw.y, kf + 4);
    float s = 0.f;
    #pragma unroll
    for (int j = 0; j < 8; ++j) s += qf[j] * kf[j];
    s += __shfl_xor(s, 1);
    s += __shfl_xor(s, 2);             // 4 sub-lanes = one head's 32 dims
    const float ex = valid ? fast_exp2(s) : 0.f;   // log2e folded into k
    z += ex;
    fp8x4_dec(vw.x, vf); fp8x4_dec(vw.y, vf + 4);
    #pragma unroll
    for (int j = 0; j < 8; ++j) acc[j] += ex * vf[j];
}

__global__ __launch_bounds__(256) void aggregate(
    const u16* __restrict__ qb, const u8* __restrict__ kv8, const int* __restrict__ off,
    const int* __restrict__ esrc, u16* __restrict__ tout)
{
    const int wid = blockIdx.x * 4 + (threadIdx.x >> 6);
    const int lane = threadIdx.x & 63;
    const int half = lane >> 5, sl = lane & 31;
    if (wid >= MPAD) return;
    if (wid >= NN) {                   // zero pad rows for the downstream GEMM
        if (half == 0) *(u16x8*)(tout + (size_t)wid * 256 + sl * 8) = (u16x8)0;
        return;
    }
    const u16x8 qv = *(const u16x8*)(qb + (size_t)wid * 256 + sl * 8);
    float qf[8];
    #pragma unroll
    for (int j = 0; j < 8; ++j) qf[j] = bf2f(qv[j]);
    float acc[8] = {0.f, 0.f, 0.f, 0.f, 0.f, 0.f, 0.f, 0.f};
    float z = 0.f;
    const int e0 = off[wid], e1 = off[wid + 1];
    for (int c0 = e0; c0 < e1; c0 += 64) {
        const int cnt = min(64, e1 - c0);
        const int jj = c0 + lane;
        const int myid = (jj < e1) ? esrc[jj] : 0;   // chunk ids in registers
        for (int i = 0; i < cnt; i += 8) {           // 8 edges / iteration (4 per half)
            const int i0 = i + half,     i1 = i + 2 + half;
            const int i2 = i + 4 + half, i3 = i + 6 + half;
            const int id0 = __shfl(myid, i0), id1 = __shfl(myid, i1);
            const int id2 = __shfl(myid, i2), id3 = __shfl(myid, i3);
            agg_edge(kv8, id0, i0 < cnt, qf, sl, z, acc);
            agg_edge(kv8, id1, i1 < cnt, qf, sl, z, acc);
            agg_edge(kv8, id2, i2 < cnt, qf, sl, z, acc);
            agg_edge(kv8, id3, i3 < cnt, qf, sl, z, acc);
        }
    }
    #pragma unroll
    for (int j = 0; j < 8; ++j) acc[j] += __shfl_xor(acc[j], 32);
    z += __shfl_xor(z, 32);
    if (half == 0) {
        const float rz = (z > 0.f) ? 1.f / z : 0.f;
        u16x8 o;
        #pragma unroll
        for (int j = 0; j < 8; ++j) o[j] = f2bf(acc[j] * rz);
        *(u16x8*)(tout + (size_t)wid * 256 + sl * 8) = o;
    }
}

// ---------------------------------------------------------------- launch
extern "C" void kernel_launch(void* const* d_in, const int* in_sizes, int n_in,
                              void* d_out, int out_size, void* d_ws, size_t ws_size,
                              hipStream_t stream)
{
    const float* h   = (const float*)d_in[0];
    const int*   src = (const int*)d_in[1];
    const int*   dst = (const int*)d_in[2];
    const float* Wk  = (const float*)d_in[3];
    const float* bk  = (const float*)d_in[4];
    const float* Wq  = (const float*)d_in[5];
    const float* bq  = (const float*)d_in[6];
    const float* Wv  = (const float*)d_in[7];
    const float* bv  = (const float*)d_in[8];
    const float* Wa  = (const float*)d_in[9];
    const float* ba  = (const float*)d_in[10];
    const float* rel_att = (const float*)d_in[11];
    const float* rel_msg = (const float*)d_in[12];
    const float* rel_pri = (const float*)d_in[13];
    const float* skip    = (const float*)d_in[14];
    float* out = (float*)d_out;

    char* w = (char*)d_ws;
    // ws layout (bytes), ~33 MB total:
    u16* h_bf  = (u16*)(w + 0);           // MPAD*256*2 = 10,289,152
    u16* W_all = (u16*)(w + 10289152);    // 768*256*2  =    393,216
    float* b_eff = (float*)(w + 10682368);// 768*4 (+pad)
    u16* Wa_bf = (u16*)(w + 10685440);    // 256*256*2  =    131,072
    u16* qb    = (u16*)(w + 10816512);    // MPAD*256*2 = 10,289,152
    u8*  kv8   = (u8*)(w + 21105664);     // MPAD*512   = 10,289,152
    int* deg   = (int*)(w + 31394816);    // 20000*4 (+pad)
    int* off   = (int*)(w + 31474944);    // 20001*4 (+pad)
    int* cur   = (int*)(w + 31555072);
    int* esrc  = (int*)(w + 31635200);    // NE*4 = 1,280,000
    u16* t_bf  = h_bf;                    // alias: h_bf dead after gemm_qkv

    zero_deg<<<20, 256, 0, stream>>>(deg);
    prep_all<<<7298, 256, 0, stream>>>(Wq, bq, Wk, bk, Wv, bv, Wa,
                                       rel_att, rel_msg, rel_pri, h, dst,
                                       W_all, b_eff, Wa_bf, h_bf, deg);
    gemm_qkv<<<dim3(157, 6), 256, 0, stream>>>(h_bf, W_all, b_eff, qb, kv8);
    scan_deg<<<1, 1024, 0, stream>>>(deg, off, cur);
    scatter_edges<<<NE / 256, 256, 0, stream>>>(dst, src, cur, esrc);
    aggregate<<<MPAD / 4, 256, 0, stream>>>(qb, kv8, off, esrc, t_bf);
    gemm_out<<<dim3(314, 4), 256, 0, stream>>>(t_bf, Wa_bf, ba, h, skip, out);
}

// Round 5
// 128.879 us; speedup vs baseline: 1.5334x; 1.0277x over previous
//
#include <hip/hip_runtime.h>
#include <hip/hip_bf16.h>
#include <math.h>

// HGT layer, MI355X. Pipeline:
//  zero_deg     : zero the degree array
//  prep_all     : fold rel_att/rel_msg (+rel_pri*log2e/sqrt(dk)) into Wk/Wv -> W_all[768,256] bf16
//                 + cast h fp32->bf16 (pad rows zero) + deg histogram (fused)
//  gemm_qkv     : [MPAD,768] = h_bf @ W_all^T + b_eff; epilogue writes q bf16,
//                 k/v OCP-fp8 INTERLEAVED per 8B (lane sl: k at row*512+sl*16, v at +8)
//  scan1/scan2  : 20-block parallel exclusive scan of deg -> off/cur (replaces the
//                 single-block 20-serial-chunk scan: 16 waves on 1 CU was latency-bound)
//  scatter      : CSR scatter (stores src per slot)
//  aggregate    : 1 wave/node, half-wave per edge, ONE uint4 (16B) k+v load per lane
//                 per edge, 16 edges/iter (8 gathers in flight per half-wave)
//  gemm_out     : 64x64 tiles; out = (t_bf @ Wa^T + ba)*alpha + h*(1-alpha)

#define NN   20000
#define NE   320000
#define MPAD 20096   // 157*128 = 314*64

typedef unsigned short u16;
typedef unsigned char  u8;
typedef __bf16 bf16x8 __attribute__((ext_vector_type(8)));
typedef u16    u16x8  __attribute__((ext_vector_type(8)));
typedef float  f32x4  __attribute__((ext_vector_type(4)));

__device__ __forceinline__ float bf2f(u16 x) {
    union { float f; unsigned u; } c; c.u = ((unsigned)x) << 16; return c.f;
}
__device__ __forceinline__ u16 f2bf(float f) {
    union { float f; unsigned u; } c; c.f = f;
    unsigned r = c.u + 0x7fffu + ((c.u >> 16) & 1u);
    return (u16)(r >> 16);
}

#if __has_builtin(__builtin_amdgcn_cvt_pk_fp8_f32) && __has_builtin(__builtin_amdgcn_cvt_pk_f32_fp8)
#define HWFP8 1
#else
#define HWFP8 0
#endif

__device__ __forceinline__ u8 f2fp8(float x) {
#if HWFP8
    return (u8)(__builtin_amdgcn_cvt_pk_fp8_f32(x, x, 0, false) & 0xff);
#else
    if (x != x) return 0x7f;
    unsigned sg = (x < 0.f) ? 0x80u : 0u;
    float a = fabsf(x); if (a > 448.f) a = 448.f;
    if (a < 0.015625f) {
        int m = (int)rintf(a * 512.f);
        if (m > 7) return (u8)(sg | 0x08);
        return (u8)(sg | m);
    }
    int e; (void)frexpf(a, &e);
    int p = e - 1;
    float mant = a * exp2f((float)(-p));
    int m = (int)rintf((mant - 1.f) * 8.f);
    int ef = p + 7;
    if (m == 8) { m = 0; ef++; }
    if (ef > 15) { ef = 15; m = 6; }
    return (u8)(sg | (ef << 3) | m);
#endif
}

__device__ __forceinline__ void fp8x4_dec(unsigned w, float* o) {
#if HWFP8
    auto lo = __builtin_amdgcn_cvt_pk_f32_fp8(w, false);
    auto hi = __builtin_amdgcn_cvt_pk_f32_fp8(w, true);
    o[0] = lo[0]; o[1] = lo[1]; o[2] = hi[0]; o[3] = hi[1];
#else
    #pragma unroll
    for (int j = 0; j < 4; ++j) {
        u8 b = (w >> (8 * j)) & 0xff;
        unsigned e = (b >> 3) & 15, m = b & 7;
        float v;
        if (e) { union { unsigned u; float f; } c; c.u = ((e + 120) << 23) | (m << 20); v = c.f; }
        else v = (float)m * 0.001953125f;
        o[j] = (b & 0x80) ? -v : v;
    }
#endif
}

__device__ __forceinline__ float fast_exp2(float x) {
#if __has_builtin(__builtin_amdgcn_exp2f)
    return __builtin_amdgcn_exp2f(x);
#else
    return exp2f(x);
#endif
}

__device__ __forceinline__ void gload_lds16(const void* g, void* l) {
    __builtin_amdgcn_global_load_lds(
        (const __attribute__((address_space(1))) unsigned*)g,
        (__attribute__((address_space(3))) unsigned*)l, 16, 0, 0);
}

// ---------------------------------------------------------------- zero deg (80 KB)
__global__ void zero_deg(int* __restrict__ deg)
{
    const int i = blockIdx.x * 256 + threadIdx.x;
    if (i * 4 < NN + 64) *(int4*)(deg + i * 4) = make_int4(0, 0, 0, 0);
}

// ---------------------------------------------------------------- prep (weights + h cast + deg)
__global__ void prep_all(const float* __restrict__ Wq, const float* __restrict__ bq,
                         const float* __restrict__ Wk, const float* __restrict__ bk,
                         const float* __restrict__ Wv, const float* __restrict__ bv,
                         const float* __restrict__ Wa,
                         const float* __restrict__ rel_att, const float* __restrict__ rel_msg,
                         const float* __restrict__ rel_pri,
                         const float* __restrict__ h, const int* __restrict__ dst,
                         u16* __restrict__ W_all, float* __restrict__ b_eff,
                         u16* __restrict__ Wa_bf, u16* __restrict__ hb, int* __restrict__ deg)
{
    const int bid = blockIdx.x, t = threadIdx.x;
    if (bid < 768) {
        const int row = bid, col = t;
        float val;
        if (row < 256) {
            val = Wq[row * 256 + col];
            if (col == 0) b_eff[row] = bq[row];
        } else if (row < 512) {
            const int r = row - 256, hh = r >> 5, e = r & 31;
            // rel_pri / sqrt(32) * log2(e) -> aggregate uses exp2 directly
            const float s = rel_pri[hh] * 0.17677669529663687f * 1.4426950408889634f;
            float acc = 0.f;
            for (int d = 0; d < 32; ++d)
                acc += rel_att[hh * 1024 + d * 32 + e] * Wk[(hh * 32 + d) * 256 + col];
            val = acc * s;
            if (col == 0) {
                float b = 0.f;
                for (int d = 0; d < 32; ++d) b += rel_att[hh * 1024 + d * 32 + e] * bk[hh * 32 + d];
                b_eff[row] = b * s;
            }
        } else {
            const int r = row - 512, hh = r >> 5, e = r & 31;
            float acc = 0.f;
            for (int d = 0; d < 32; ++d)
                acc += rel_msg[hh * 1024 + d * 32 + e] * Wv[(hh * 32 + d) * 256 + col];
            val = acc;
            if (col == 0) {
                float b = 0.f;
                for (int d = 0; d < 32; ++d) b += rel_msg[hh * 1024 + d * 32 + e] * bv[hh * 32 + d];
                b_eff[row] = b;
            }
        }
        W_all[row * 256 + col] = f2bf(val);
    } else if (bid < 1024) {
        const int idx = (bid - 768) * 256 + t;
        Wa_bf[idx] = f2bf(Wa[idx]);
    } else if (bid < 6048) {
        const int i = (bid - 1024) * 256 + t;  // one ushort4 per thread
        const int row = i >> 6, c4 = (i & 63) * 4;
        if (row >= MPAD) return;
        ushort4 o;
        if (row < NN) {
            const float4 v = *(const float4*)(h + (size_t)row * 256 + c4);
            o.x = f2bf(v.x); o.y = f2bf(v.y); o.z = f2bf(v.z); o.w = f2bf(v.w);
        } else {
            o = make_ushort4(0, 0, 0, 0);
        }
        *(ushort4*)(hb + (size_t)row * 256 + c4) = o;
    } else {
        const int e = (bid - 6048) * 256 + t;
        if (e < NE) atomicAdd(&deg[dst[e]], 1);
    }
}

// ---------------------------------------------------------------- GEMM qkv
// Epilogue: q bf16; k/v fp8 interleaved: dim d of k -> row*512 + (d>>3)*16 + (d&7),
//                                        dim d of v -> row*512 + (d>>3)*16 + 8 + (d&7)
__global__ __launch_bounds__(256) void gemm_qkv(
    const u16* __restrict__ A, const u16* __restrict__ B,
    const float* __restrict__ bias, u16* __restrict__ qb, u8* __restrict__ kv8)
{
    __shared__ u16 At[128 * 64];
    __shared__ u16 Bt[128 * 64];
    const int t = threadIdx.x;
    const int wave = t >> 6, lane = t & 63;
    const int row0 = blockIdx.x * 128, col0 = blockIdx.y * 128;
    const int wm = (wave >> 1) * 64, wn = (wave & 1) * 64;
    const int cl = lane & 15, rh = lane >> 4;
    const int srow = t >> 3, scol = (t & 7) * 8;

    f32x4 acc[4][4] = {};

    for (int k0 = 0; k0 < 256; k0 += 64) {
        __syncthreads();
        #pragma unroll
        for (int r = 0; r < 4; ++r) {
            const int rowT = r * 32 + srow;
            gload_lds16(A + (size_t)(row0 + rowT) * 256 + k0 + scol, &At[(r * 256 + wave * 64) * 8]);
            gload_lds16(B + (size_t)(col0 + rowT) * 256 + k0 + scol, &Bt[(r * 256 + wave * 64) * 8]);
        }
        __syncthreads();
        #pragma unroll
        for (int kk = 0; kk < 64; kk += 32) {
            bf16x8 af[4], bb[4];
            #pragma unroll
            for (int m = 0; m < 4; ++m)
                af[m] = *(const bf16x8*)&At[(wm + 16 * m + cl) * 64 + kk + rh * 8];
            #pragma unroll
            for (int n = 0; n < 4; ++n)
                bb[n] = *(const bf16x8*)&Bt[(wn + 16 * n + cl) * 64 + kk + rh * 8];
            #pragma unroll
            for (int m = 0; m < 4; ++m)
                #pragma unroll
                for (int n = 0; n < 4; ++n)
                    acc[m][n] = __builtin_amdgcn_mfma_f32_16x16x32_bf16(af[m], bb[n], acc[m][n], 0, 0, 0);
        }
    }
    #pragma unroll
    for (int n = 0; n < 4; ++n) {
        const int col = col0 + wn + 16 * n + cl;
        const float bv = bias[col];
        #pragma unroll
        for (int m = 0; m < 4; ++m) {
            const int rowb = row0 + wm + 16 * m + 4 * rh;
            #pragma unroll
            for (int r = 0; r < 4; ++r) {
                const float val = acc[m][n][r] + bv;
                const size_t row = (size_t)(rowb + r);
                if (col < 256) {
                    qb[row * 256 + col] = f2bf(val);
                } else if (col < 512) {
                    const int d = col - 256;
                    kv8[row * 512 + ((d >> 3) << 4) + (d & 7)] = f2fp8(val);
                } else {
                    const int d = col - 512;
                    kv8[row * 512 + ((d >> 3) << 4) + 8 + (d & 7)] = f2fp8(val);
                }
            }
        }
    }
}

// ---------------------------------------------------------------- GEMM out (64x64 tiles, fp32 out)
__global__ __launch_bounds__(256) void gemm_out(
    const u16* __restrict__ A, const u16* __restrict__ B,
    const float* __restrict__ bias, const float* __restrict__ hres,
    const float* __restrict__ skip, float* __restrict__ C)
{
    __shared__ u16 At[64 * 64];
    __shared__ u16 Bt[64 * 64];
    const int t = threadIdx.x;
    const int wave = t >> 6, lane = t & 63;
    const int row0 = blockIdx.x * 64, col0 = blockIdx.y * 64;
    const int wm = (wave >> 1) * 32, wn = (wave & 1) * 32;
    const int cl = lane & 15, rh = lane >> 4;
    const int srow = t >> 3, scol = (t & 7) * 8;

    f32x4 acc[2][2] = {};

    for (int k0 = 0; k0 < 256; k0 += 64) {
        __syncthreads();
        #pragma unroll
        for (int r = 0; r < 2; ++r) {
            const int rowT = r * 32 + srow;
            gload_lds16(A + (size_t)(row0 + rowT) * 256 + k0 + scol, &At[(r * 2048 + wave * 512)]);
            gload_lds16(B + (size_t)(col0 + rowT) * 256 + k0 + scol, &Bt[(r * 2048 + wave * 512)]);
        }
        __syncthreads();
        #pragma unroll
        for (int kk = 0; kk < 64; kk += 32) {
            bf16x8 af[2], bb[2];
            #pragma unroll
            for (int m = 0; m < 2; ++m)
                af[m] = *(const bf16x8*)&At[(wm + 16 * m + cl) * 64 + kk + rh * 8];
            #pragma unroll
            for (int n = 0; n < 2; ++n)
                bb[n] = *(const bf16x8*)&Bt[(wn + 16 * n + cl) * 64 + kk + rh * 8];
            #pragma unroll
            for (int m = 0; m < 2; ++m)
                #pragma unroll
                for (int n = 0; n < 2; ++n)
                    acc[m][n] = __builtin_amdgcn_mfma_f32_16x16x32_bf16(af[m], bb[n], acc[m][n], 0, 0, 0);
        }
    }
    const float alpha = 1.f / (1.f + __expf(-skip[0]));
    const float beta = 1.f - alpha;
    #pragma unroll
    for (int n = 0; n < 2; ++n) {
        const int col = col0 + wn + 16 * n + cl;
        const float bv = bias[col];
        #pragma unroll
        for (int m = 0; m < 2; ++m) {
            const int rowb = row0 + wm + 16 * m + 4 * rh;
            #pragma unroll
            for (int r = 0; r < 4; ++r) {
                const int row = rowb + r;
                if (row < NN)
                    C[(size_t)row * 256 + col] =
                        (acc[m][n][r] + bv) * alpha + hres[(size_t)row * 256 + col] * beta;
            }
        }
    }
}

// ---------------------------------------------------------------- parallel scan (20 blocks)
// scan1: block-local exclusive scan into off + block total into bsum
__global__ __launch_bounds__(1024) void scan1(const int* __restrict__ deg,
                                              int* __restrict__ off, int* __restrict__ bsum)
{
    __shared__ int wsum[16];
    __shared__ int wpre[16];
    const int t = threadIdx.x, b = blockIdx.x;
    const int i = b * 1024 + t;
    const int lane = t & 63, wv = t >> 6;
    const int v = (i < NN) ? deg[i] : 0;
    int s = v;
    #pragma unroll
    for (int o = 1; o < 64; o <<= 1) {
        const int u = __shfl_up(s, o);
        if (lane >= o) s += u;
    }
    if (lane == 63) wsum[wv] = s;
    __syncthreads();
    if (wv == 0) {
        const int x = (lane < 16) ? wsum[lane] : 0;
        int sx = x;
        #pragma unroll
        for (int o = 1; o < 16; o <<= 1) {
            const int u = __shfl_up(sx, o);
            if (lane >= o) sx += u;
        }
        if (lane < 16) wpre[lane] = sx - x;
    }
    __syncthreads();
    const int incl = s + wpre[wv];
    if (i < NN) off[i] = incl - v;      // block-local exclusive
    if (t == 1023) bsum[b] = incl;      // block total
}

// scan2: add block-prefix, write cur, and off[NN]
__global__ __launch_bounds__(1024) void scan2(const int* __restrict__ bsum,
                                              int* __restrict__ off, int* __restrict__ cur)
{
    __shared__ int pre;
    const int t = threadIdx.x, b = blockIdx.x;
    const int i = b * 1024 + t;
    if (t == 0) {
        int p = 0;
        for (int j = 0; j < b; ++j) p += bsum[j];
        pre = p;
    }
    __syncthreads();
    if (i < NN) {
        const int o = off[i] + pre;
        off[i] = o; cur[i] = o;
    }
    if (b == 19 && t == 0) {
        int tot = pre + bsum[19];
        off[NN] = tot;
    }
}

__global__ void scatter_edges(const int* __restrict__ dst, const int* __restrict__ src,
                              int* __restrict__ cur, int* __restrict__ esrc)
{
    const int e = blockIdx.x * 256 + threadIdx.x;
    if (e < NE) {
        const int p = atomicAdd(&cur[dst[e]], 1);
        esrc[p] = src[e];
    }
}

// ---------------------------------------------------------------- aggregation (1 wave / node)
// half-wave per edge: sub-lane sl (0..31) owns dims [8sl,8sl+8); head = sl>>2.
// ONE uint4 load per lane per edge (k bytes 0..7, v bytes 8..15 of the lane's 16B).
__device__ __forceinline__ void agg_edge(const u8* __restrict__ kv8, int id, bool valid,
                                         const float* qf, int sl, float& z, float* acc)
{
    const uint4 w = *(const uint4*)(kv8 + (size_t)id * 512 + sl * 16);
    float kf[8], vf[8];
    fp8x4_dec(w.x, kf); fp8x4_dec(w.y, kf + 4);
    float s = 0.f;
    #pragma unroll
    for (int j = 0; j < 8; ++j) s += qf[j] * kf[j];
    s += __shfl_xor(s, 1);
    s += __shfl_xor(s, 2);             // 4 sub-lanes = one head's 32 dims
    const float ex = valid ? fast_exp2(s) : 0.f;   // log2e folded into k
    z += ex;
    fp8x4_dec(w.z, vf); fp8x4_dec(w.w, vf + 4);
    #pragma unroll
    for (int j = 0; j < 8; ++j) acc[j] += ex * vf[j];
}

__global__ __launch_bounds__(256) void aggregate(
    const u16* __restrict__ qb, const u8* __restrict__ kv8, const int* __restrict__ off,
    const int* __restrict__ esrc, u16* __restrict__ tout)
{
    const int wid = blockIdx.x * 4 + (threadIdx.x >> 6);
    const int lane = threadIdx.x & 63;
    const int half = lane >> 5, sl = lane & 31;
    if (wid >= MPAD) return;
    if (wid >= NN) {                   // zero pad rows for the downstream GEMM
        if (half == 0) *(u16x8*)(tout + (size_t)wid * 256 + sl * 8) = (u16x8)0;
        return;
    }
    const u16x8 qv = *(const u16x8*)(qb + (size_t)wid * 256 + sl * 8);
    float qf[8];
    #pragma unroll
    for (int j = 0; j < 8; ++j) qf[j] = bf2f(qv[j]);
    float acc[8] = {0.f, 0.f, 0.f, 0.f, 0.f, 0.f, 0.f, 0.f};
    float z = 0.f;
    const int e0 = off[wid], e1 = off[wid + 1];
    for (int c0 = e0; c0 < e1; c0 += 64) {
        const int cnt = min(64, e1 - c0);
        const int jj = c0 + lane;
        const int myid = (jj < e1) ? esrc[jj] : 0;   // chunk ids in registers
        for (int i = 0; i < cnt; i += 16) {          // 16 edges / iter (8 per half)
            int ii[8], idv[8];
            #pragma unroll
            for (int j = 0; j < 8; ++j) {
                ii[j] = i + 2 * j + half;
                idv[j] = __shfl(myid, ii[j]);
            }
            #pragma unroll
            for (int j = 0; j < 8; ++j)
                agg_edge(kv8, idv[j], ii[j] < cnt, qf, sl, z, acc);
        }
    }
    #pragma unroll
    for (int j = 0; j < 8; ++j) acc[j] += __shfl_xor(acc[j], 32);
    z += __shfl_xor(z, 32);
    if (half == 0) {
        const float rz = (z > 0.f) ? 1.f / z : 0.f;
        u16x8 o;
        #pragma unroll
        for (int j = 0; j < 8; ++j) o[j] = f2bf(acc[j] * rz);
        *(u16x8*)(tout + (size_t)wid * 256 + sl * 8) = o;
    }
}

// ---------------------------------------------------------------- launch
extern "C" void kernel_launch(void* const* d_in, const int* in_sizes, int n_in,
                              void* d_out, int out_size, void* d_ws, size_t ws_size,
                              hipStream_t stream)
{
    const float* h   = (const float*)d_in[0];
    const int*   src = (const int*)d_in[1];
    const int*   dst = (const int*)d_in[2];
    const float* Wk  = (const float*)d_in[3];
    const float* bk  = (const float*)d_in[4];
    const float* Wq  = (const float*)d_in[5];
    const float* bq  = (const float*)d_in[6];
    const float* Wv  = (const float*)d_in[7];
    const float* bv  = (const float*)d_in[8];
    const float* Wa  = (const float*)d_in[9];
    const float* ba  = (const float*)d_in[10];
    const float* rel_att = (const float*)d_in[11];
    const float* rel_msg = (const float*)d_in[12];
    const float* rel_pri = (const float*)d_in[13];
    const float* skip    = (const float*)d_in[14];
    float* out = (float*)d_out;

    char* w = (char*)d_ws;
    u16* h_bf  = (u16*)(w + 0);           // MPAD*256*2 = 10,289,152
    u16* W_all = (u16*)(w + 10289152);    // 768*256*2
    float* b_eff = (float*)(w + 10682368);
    u16* Wa_bf = (u16*)(w + 10685440);    // 256*256*2
    u16* qb    = (u16*)(w + 10816512);    // MPAD*256*2
    u8*  kv8   = (u8*)(w + 21105664);     // MPAD*512
    int* deg   = (int*)(w + 31394816);
    int* off   = (int*)(w + 31474944);
    int* cur   = (int*)(w + 31555072);
    int* bsum  = (int*)(w + 31635200);    // 20*4 (+pad)
    int* esrc  = (int*)(w + 31636224);    // NE*4
    u16* t_bf  = h_bf;                    // alias: h_bf dead after gemm_qkv

    zero_deg<<<20, 256, 0, stream>>>(deg);
    prep_all<<<7298, 256, 0, stream>>>(Wq, bq, Wk, bk, Wv, bv, Wa,
                                       rel_att, rel_msg, rel_pri, h, dst,
                                       W_all, b_eff, Wa_bf, h_bf, deg);
    gemm_qkv<<<dim3(157, 6), 256, 0, stream>>>(h_bf, W_all, b_eff, qb, kv8);
    scan1<<<20, 1024, 0, stream>>>(deg, off, bsum);
    scan2<<<20, 1024, 0, stream>>>(bsum, off, cur);
    scatter_edges<<<NE / 256, 256, 0, stream>>>(dst, src, cur, esrc);
    aggregate<<<MPAD / 4, 256, 0, stream>>>(qb, kv8, off, esrc, t_bf);
    gemm_out<<<dim3(314, 4), 256, 0, stream>>>(t_bf, Wa_bf, ba, h, skip, out);
}

// Round 6
// 118.750 us; speedup vs baseline: 1.6641x; 1.0853x over previous
//
#include <hip/hip_runtime.h>
#include <hip/hip_bf16.h>
#include <math.h>

// HGT layer, MI355X. Pipeline (6 dispatches):
//  prep0        : zero deg (blocks 0-19) || fold rel_att/rel_msg (+rel_pri*log2e/sqrt(dk))
//                 into Wk/Wv -> W_all[768,256] bf16 (blocks 20-787) || cast Wa (788-1043)
//  gemm_qkv     : blocks 0-941: [MPAD,768] = cast_bf16(h) @ W_all^T + b_eff
//                 (A fp32->bf16 cast fused into reg-staging; h_bf pass eliminated);
//                 epilogue: q bf16, k/v OCP-fp8 interleaved per 8B.
//                 blocks 942-2191: deg histogram (independent of qkv part).
//  scan1/scan2  : 20-block parallel exclusive scan of deg -> off/cur
//  scatter      : CSR scatter (stores src per slot)
//  aggregate    : 1 wave/node, half-wave per edge, ONE uint4 (16B) k+v load per lane per
//                 edge, 16 edges/iter; invalid tail edges now SKIPPED (exec-masked), no
//                 wasted gathers.
//  gemm_out     : 64x64 tiles; out = (t_bf @ Wa^T + ba)*alpha + h*(1-alpha)

#define NN   20000
#define NE   320000
#define MPAD 20096   // 157*128 = 314*64

typedef unsigned short u16;
typedef unsigned char  u8;
typedef __bf16 bf16x8 __attribute__((ext_vector_type(8)));
typedef u16    u16x8  __attribute__((ext_vector_type(8)));
typedef float  f32x4  __attribute__((ext_vector_type(4)));

__device__ __forceinline__ float bf2f(u16 x) {
    union { float f; unsigned u; } c; c.u = ((unsigned)x) << 16; return c.f;
}
__device__ __forceinline__ u16 f2bf(float f) {
    union { float f; unsigned u; } c; c.f = f;
    unsigned r = c.u + 0x7fffu + ((c.u >> 16) & 1u);
    return (u16)(r >> 16);
}

#if __has_builtin(__builtin_amdgcn_cvt_pk_fp8_f32) && __has_builtin(__builtin_amdgcn_cvt_pk_f32_fp8)
#define HWFP8 1
#else
#define HWFP8 0
#endif

__device__ __forceinline__ u8 f2fp8(float x) {
#if HWFP8
    return (u8)(__builtin_amdgcn_cvt_pk_fp8_f32(x, x, 0, false) & 0xff);
#else
    if (x != x) return 0x7f;
    unsigned sg = (x < 0.f) ? 0x80u : 0u;
    float a = fabsf(x); if (a > 448.f) a = 448.f;
    if (a < 0.015625f) {
        int m = (int)rintf(a * 512.f);
        if (m > 7) return (u8)(sg | 0x08);
        return (u8)(sg | m);
    }
    int e; (void)frexpf(a, &e);
    int p = e - 1;
    float mant = a * exp2f((float)(-p));
    int m = (int)rintf((mant - 1.f) * 8.f);
    int ef = p + 7;
    if (m == 8) { m = 0; ef++; }
    if (ef > 15) { ef = 15; m = 6; }
    return (u8)(sg | (ef << 3) | m);
#endif
}

__device__ __forceinline__ void fp8x4_dec(unsigned w, float* o) {
#if HWFP8
    auto lo = __builtin_amdgcn_cvt_pk_f32_fp8(w, false);
    auto hi = __builtin_amdgcn_cvt_pk_f32_fp8(w, true);
    o[0] = lo[0]; o[1] = lo[1]; o[2] = hi[0]; o[3] = hi[1];
#else
    #pragma unroll
    for (int j = 0; j < 4; ++j) {
        u8 b = (w >> (8 * j)) & 0xff;
        unsigned e = (b >> 3) & 15, m = b & 7;
        float v;
        if (e) { union { unsigned u; float f; } c; c.u = ((e + 120) << 23) | (m << 20); v = c.f; }
        else v = (float)m * 0.001953125f;
        o[j] = (b & 0x80) ? -v : v;
    }
#endif
}

__device__ __forceinline__ float fast_exp2(float x) {
#if __has_builtin(__builtin_amdgcn_exp2f)
    return __builtin_amdgcn_exp2f(x);
#else
    return exp2f(x);
#endif
}

__device__ __forceinline__ void gload_lds16(const void* g, void* l) {
    __builtin_amdgcn_global_load_lds(
        (const __attribute__((address_space(1))) unsigned*)g,
        (__attribute__((address_space(3))) unsigned*)l, 16, 0, 0);
}

// ---------------------------------------------------------------- prep0: zero deg || weights
// blocks 0..19    : zero deg (5024 int4 = 20096 ints)
// blocks 20..787  : row of W_all (0-255 Wq, 256-511 rel_att*Wk*scale, 512-767 rel_msg*Wv)
// blocks 788..1043: cast Wa -> bf16
__global__ void prep0(const float* __restrict__ Wq, const float* __restrict__ bq,
                      const float* __restrict__ Wk, const float* __restrict__ bk,
                      const float* __restrict__ Wv, const float* __restrict__ bv,
                      const float* __restrict__ Wa,
                      const float* __restrict__ rel_att, const float* __restrict__ rel_msg,
                      const float* __restrict__ rel_pri,
                      u16* __restrict__ W_all, float* __restrict__ b_eff,
                      u16* __restrict__ Wa_bf, int* __restrict__ deg)
{
    const int bid = blockIdx.x, t = threadIdx.x;
    if (bid < 20) {
        const int i = bid * 256 + t;
        if (i < 5024) *(int4*)(deg + i * 4) = make_int4(0, 0, 0, 0);
    } else if (bid < 788) {
        const int row = bid - 20, col = t;
        float val;
        if (row < 256) {
            val = Wq[row * 256 + col];
            if (col == 0) b_eff[row] = bq[row];
        } else if (row < 512) {
            const int r = row - 256, hh = r >> 5, e = r & 31;
            // rel_pri / sqrt(32) * log2(e) -> aggregate uses exp2 directly
            const float s = rel_pri[hh] * 0.17677669529663687f * 1.4426950408889634f;
            float acc = 0.f;
            for (int d = 0; d < 32; ++d)
                acc += rel_att[hh * 1024 + d * 32 + e] * Wk[(hh * 32 + d) * 256 + col];
            val = acc * s;
            if (col == 0) {
                float b = 0.f;
                for (int d = 0; d < 32; ++d) b += rel_att[hh * 1024 + d * 32 + e] * bk[hh * 32 + d];
                b_eff[row] = b * s;
            }
        } else {
            const int r = row - 512, hh = r >> 5, e = r & 31;
            float acc = 0.f;
            for (int d = 0; d < 32; ++d)
                acc += rel_msg[hh * 1024 + d * 32 + e] * Wv[(hh * 32 + d) * 256 + col];
            val = acc;
            if (col == 0) {
                float b = 0.f;
                for (int d = 0; d < 32; ++d) b += rel_msg[hh * 1024 + d * 32 + e] * bv[hh * 32 + d];
                b_eff[row] = b;
            }
        }
        W_all[row * 256 + col] = f2bf(val);
    } else {
        const int idx = (bid - 788) * 256 + t;
        Wa_bf[idx] = f2bf(Wa[idx]);
    }
}

// ---------------------------------------------------------------- GEMM qkv + histogram
// blocks 0..941: qkv GEMM; A = h (fp32, cast to bf16 during reg-staging), B = W_all.
// Epilogue: q bf16; k/v fp8 interleaved (dim d of k -> row*512+(d>>3)*16+(d&7); v at +8).
// blocks 942..2191: deg histogram (needs only zeroed deg from prep0).
__global__ __launch_bounds__(256) void gemm_qkv(
    const float* __restrict__ h, const u16* __restrict__ B,
    const float* __restrict__ bias, const int* __restrict__ dst,
    u16* __restrict__ qb, u8* __restrict__ kv8, int* __restrict__ deg)
{
    if (blockIdx.x >= 942) {   // histogram part
        const int e = (blockIdx.x - 942) * 256 + threadIdx.x;
        if (e < NE) atomicAdd(&deg[dst[e]], 1);
        return;
    }
    __shared__ u16 At[128 * 64];
    __shared__ u16 Bt[128 * 64];
    const int t = threadIdx.x;
    const int wave = t >> 6, lane = t & 63;
    const int row0 = (blockIdx.x % 157) * 128, col0 = (blockIdx.x / 157) * 128;
    const int wm = (wave >> 1) * 64, wn = (wave & 1) * 64;
    const int cl = lane & 15, rh = lane >> 4;
    const int srow = t >> 3, scol = (t & 7) * 8;

    f32x4 acc[4][4] = {};

    for (int k0 = 0; k0 < 256; k0 += 64) {
        __syncthreads();
        #pragma unroll
        for (int r = 0; r < 4; ++r) {
            const int rT = r * 32 + srow;
            const int grow = row0 + rT;
            u16x8 w8 = (u16x8)0;
            if (grow < NN) {
                const float4 f0 = *(const float4*)(h + (size_t)grow * 256 + k0 + scol);
                const float4 f1 = *(const float4*)(h + (size_t)grow * 256 + k0 + scol + 4);
                w8[0] = f2bf(f0.x); w8[1] = f2bf(f0.y); w8[2] = f2bf(f0.z); w8[3] = f2bf(f0.w);
                w8[4] = f2bf(f1.x); w8[5] = f2bf(f1.y); w8[6] = f2bf(f1.z); w8[7] = f2bf(f1.w);
            }
            *(u16x8*)&At[rT * 64 + scol] = w8;      // same layout as lane-linear gload
            gload_lds16(B + (size_t)(col0 + rT) * 256 + k0 + scol, &Bt[(r * 256 + wave * 64) * 8]);
        }
        __syncthreads();
        #pragma unroll
        for (int kk = 0; kk < 64; kk += 32) {
            bf16x8 af[4], bb[4];
            #pragma unroll
            for (int m = 0; m < 4; ++m)
                af[m] = *(const bf16x8*)&At[(wm + 16 * m + cl) * 64 + kk + rh * 8];
            #pragma unroll
            for (int n = 0; n < 4; ++n)
                bb[n] = *(const bf16x8*)&Bt[(wn + 16 * n + cl) * 64 + kk + rh * 8];
            #pragma unroll
            for (int m = 0; m < 4; ++m)
                #pragma unroll
                for (int n = 0; n < 4; ++n)
                    acc[m][n] = __builtin_amdgcn_mfma_f32_16x16x32_bf16(af[m], bb[n], acc[m][n], 0, 0, 0);
        }
    }
    #pragma unroll
    for (int n = 0; n < 4; ++n) {
        const int col = col0 + wn + 16 * n + cl;
        const float bv = bias[col];
        #pragma unroll
        for (int m = 0; m < 4; ++m) {
            const int rowb = row0 + wm + 16 * m + 4 * rh;
            #pragma unroll
            for (int r = 0; r < 4; ++r) {
                const float val = acc[m][n][r] + bv;
                const size_t row = (size_t)(rowb + r);
                if (col < 256) {
                    qb[row * 256 + col] = f2bf(val);
                } else if (col < 512) {
                    const int d = col - 256;
                    kv8[row * 512 + ((d >> 3) << 4) + (d & 7)] = f2fp8(val);
                } else {
                    const int d = col - 512;
                    kv8[row * 512 + ((d >> 3) << 4) + 8 + (d & 7)] = f2fp8(val);
                }
            }
        }
    }
}

// ---------------------------------------------------------------- GEMM out (64x64 tiles, fp32 out)
__global__ __launch_bounds__(256) void gemm_out(
    const u16* __restrict__ A, const u16* __restrict__ B,
    const float* __restrict__ bias, const float* __restrict__ hres,
    const float* __restrict__ skip, float* __restrict__ C)
{
    __shared__ u16 At[64 * 64];
    __shared__ u16 Bt[64 * 64];
    const int t = threadIdx.x;
    const int wave = t >> 6, lane = t & 63;
    const int row0 = blockIdx.x * 64, col0 = blockIdx.y * 64;
    const int wm = (wave >> 1) * 32, wn = (wave & 1) * 32;
    const int cl = lane & 15, rh = lane >> 4;
    const int srow = t >> 3, scol = (t & 7) * 8;

    f32x4 acc[2][2] = {};

    for (int k0 = 0; k0 < 256; k0 += 64) {
        __syncthreads();
        #pragma unroll
        for (int r = 0; r < 2; ++r) {
            const int rowT = r * 32 + srow;
            gload_lds16(A + (size_t)(row0 + rowT) * 256 + k0 + scol, &At[(r * 2048 + wave * 512)]);
            gload_lds16(B + (size_t)(col0 + rowT) * 256 + k0 + scol, &Bt[(r * 2048 + wave * 512)]);
        }
        __syncthreads();
        #pragma unroll
        for (int kk = 0; kk < 64; kk += 32) {
            bf16x8 af[2], bb[2];
            #pragma unroll
            for (int m = 0; m < 2; ++m)
                af[m] = *(const bf16x8*)&At[(wm + 16 * m + cl) * 64 + kk + rh * 8];
            #pragma unroll
            for (int n = 0; n < 2; ++n)
                bb[n] = *(const bf16x8*)&Bt[(wn + 16 * n + cl) * 64 + kk + rh * 8];
            #pragma unroll
            for (int m = 0; m < 2; ++m)
                #pragma unroll
                for (int n = 0; n < 2; ++n)
                    acc[m][n] = __builtin_amdgcn_mfma_f32_16x16x32_bf16(af[m], bb[n], acc[m][n], 0, 0, 0);
        }
    }
    const float alpha = 1.f / (1.f + __expf(-skip[0]));
    const float beta = 1.f - alpha;
    #pragma unroll
    for (int n = 0; n < 2; ++n) {
        const int col = col0 + wn + 16 * n + cl;
        const float bv = bias[col];
        #pragma unroll
        for (int m = 0; m < 2; ++m) {
            const int rowb = row0 + wm + 16 * m + 4 * rh;
            #pragma unroll
            for (int r = 0; r < 4; ++r) {
                const int row = rowb + r;
                if (row < NN)
                    C[(size_t)row * 256 + col] =
                        (acc[m][n][r] + bv) * alpha + hres[(size_t)row * 256 + col] * beta;
            }
        }
    }
}

// ---------------------------------------------------------------- parallel scan (20 blocks)
__global__ __launch_bounds__(1024) void scan1(const int* __restrict__ deg,
                                              int* __restrict__ off, int* __restrict__ bsum)
{
    __shared__ int wsum[16];
    __shared__ int wpre[16];
    const int t = threadIdx.x, b = blockIdx.x;
    const int i = b * 1024 + t;
    const int lane = t & 63, wv = t >> 6;
    const int v = (i < NN) ? deg[i] : 0;
    int s = v;
    #pragma unroll
    for (int o = 1; o < 64; o <<= 1) {
        const int u = __shfl_up(s, o);
        if (lane >= o) s += u;
    }
    if (lane == 63) wsum[wv] = s;
    __syncthreads();
    if (wv == 0) {
        const int x = (lane < 16) ? wsum[lane] : 0;
        int sx = x;
        #pragma unroll
        for (int o = 1; o < 16; o <<= 1) {
            const int u = __shfl_up(sx, o);
            if (lane >= o) sx += u;
        }
        if (lane < 16) wpre[lane] = sx - x;
    }
    __syncthreads();
    const int incl = s + wpre[wv];
    if (i < NN) off[i] = incl - v;      // block-local exclusive
    if (t == 1023) bsum[b] = incl;      // block total
}

__global__ __launch_bounds__(1024) void scan2(const int* __restrict__ bsum,
                                              int* __restrict__ off, int* __restrict__ cur)
{
    __shared__ int pre;
    const int t = threadIdx.x, b = blockIdx.x;
    const int i = b * 1024 + t;
    if (t == 0) {
        int p = 0;
        for (int j = 0; j < b; ++j) p += bsum[j];
        pre = p;
    }
    __syncthreads();
    if (i < NN) {
        const int o = off[i] + pre;
        off[i] = o; cur[i] = o;
    }
    if (b == 19 && t == 0) off[NN] = pre + bsum[19];
}

__global__ void scatter_edges(const int* __restrict__ dst, const int* __restrict__ src,
                              int* __restrict__ cur, int* __restrict__ esrc)
{
    const int e = blockIdx.x * 256 + threadIdx.x;
    if (e < NE) {
        const int p = atomicAdd(&cur[dst[e]], 1);
        esrc[p] = src[e];
    }
}

// ---------------------------------------------------------------- aggregation (1 wave / node)
// half-wave per edge: sub-lane sl (0..31) owns dims [8sl,8sl+8); head = sl>>2.
// ONE uint4 load per lane per edge (k bytes 0..7, v bytes 8..15 of the lane's 16B).
__device__ __forceinline__ void agg_edge(const u8* __restrict__ kv8, int id,
                                         const float* qf, int sl, float& z, float* acc)
{
    const uint4 w = *(const uint4*)(kv8 + (size_t)id * 512 + sl * 16);
    float kf[8], vf[8];
    fp8x4_dec(w.x, kf); fp8x4_dec(w.y, kf + 4);
    float s = 0.f;
    #pragma unroll
    for (int j = 0; j < 8; ++j) s += qf[j] * kf[j];
    s += __shfl_xor(s, 1);
    s += __shfl_xor(s, 2);             // 4 sub-lanes = one head's 32 dims
    const float ex = fast_exp2(s);     // log2e folded into k
    z += ex;
    fp8x4_dec(w.z, vf); fp8x4_dec(w.w, vf + 4);
    #pragma unroll
    for (int j = 0; j < 8; ++j) acc[j] += ex * vf[j];
}

__global__ __launch_bounds__(256) void aggregate(
    const u16* __restrict__ qb, const u8* __restrict__ kv8, const int* __restrict__ off,
    const int* __restrict__ esrc, u16* __restrict__ tout)
{
    const int wid = blockIdx.x * 4 + (threadIdx.x >> 6);
    const int lane = threadIdx.x & 63;
    const int half = lane >> 5, sl = lane & 31;
    if (wid >= MPAD) return;
    if (wid >= NN) {                   // zero pad rows for the downstream GEMM
        if (half == 0) *(u16x8*)(tout + (size_t)wid * 256 + sl * 8) = (u16x8)0;
        return;
    }
    const u16x8 qv = *(const u16x8*)(qb + (size_t)wid * 256 + sl * 8);
    float qf[8];
    #pragma unroll
    for (int j = 0; j < 8; ++j) qf[j] = bf2f(qv[j]);
    float acc[8] = {0.f, 0.f, 0.f, 0.f, 0.f, 0.f, 0.f, 0.f};
    float z = 0.f;
    const int e0 = off[wid], e1 = off[wid + 1];
    for (int c0 = e0; c0 < e1; c0 += 64) {
        const int cnt = min(64, e1 - c0);
        const int jj = c0 + lane;
        const int myid = (jj < e1) ? esrc[jj] : 0;   // chunk ids in registers
        for (int i = 0; i < cnt; i += 16) {          // 16 edges / iter (8 per half)
            int ii[8], idv[8];
            #pragma unroll
            for (int j = 0; j < 8; ++j) {
                ii[j] = i + 2 * j + half;
                idv[j] = __shfl(myid, ii[j]);
            }
            #pragma unroll
            for (int j = 0; j < 8; ++j)
                if (ii[j] < cnt)       // uniform per half-wave: masks off the LOAD too
                    agg_edge(kv8, idv[j], qf, sl, z, acc);
        }
    }
    #pragma unroll
    for (int j = 0; j < 8; ++j) acc[j] += __shfl_xor(acc[j], 32);
    z += __shfl_xor(z, 32);
    if (half == 0) {
        const float rz = (z > 0.f) ? 1.f / z : 0.f;
        u16x8 o;
        #pragma unroll
        for (int j = 0; j < 8; ++j) o[j] = f2bf(acc[j] * rz);
        *(u16x8*)(tout + (size_t)wid * 256 + sl * 8) = o;
    }
}

// ---------------------------------------------------------------- launch
extern "C" void kernel_launch(void* const* d_in, const int* in_sizes, int n_in,
                              void* d_out, int out_size, void* d_ws, size_t ws_size,
                              hipStream_t stream)
{
    const float* h   = (const float*)d_in[0];
    const int*   src = (const int*)d_in[1];
    const int*   dst = (const int*)d_in[2];
    const float* Wk  = (const float*)d_in[3];
    const float* bk  = (const float*)d_in[4];
    const float* Wq  = (const float*)d_in[5];
    const float* bq  = (const float*)d_in[6];
    const float* Wv  = (const float*)d_in[7];
    const float* bv  = (const float*)d_in[8];
    const float* Wa  = (const float*)d_in[9];
    const float* ba  = (const float*)d_in[10];
    const float* rel_att = (const float*)d_in[11];
    const float* rel_msg = (const float*)d_in[12];
    const float* rel_pri = (const float*)d_in[13];
    const float* skip    = (const float*)d_in[14];
    float* out = (float*)d_out;

    char* w = (char*)d_ws;
    u16*   W_all = (u16*)(w + 0);         //    393,216
    float* b_eff = (float*)(w + 393216);  //      3,072 (+pad)
    u16*   Wa_bf = (u16*)(w + 396288);    //    131,072
    u16*   qb    = (u16*)(w + 527360);    // 10,289,152
    u8*    kv8   = (u8*)(w + 10816512);   // 10,289,152
    u16*   t_bf  = (u16*)(w + 21105664);  // 10,289,152
    int*   deg   = (int*)(w + 31394816);  //     80,384 (20096 ints)
    int*   off   = (int*)(w + 31475200);  //     80,384
    int*   cur   = (int*)(w + 31555584);  //     80,384
    int*   bsum  = (int*)(w + 31635968);  //        128
    int*   esrc  = (int*)(w + 31636096);  //  1,280,000

    prep0<<<1044, 256, 0, stream>>>(Wq, bq, Wk, bk, Wv, bv, Wa,
                                    rel_att, rel_msg, rel_pri,
                                    W_all, b_eff, Wa_bf, deg);
    gemm_qkv<<<942 + 1250, 256, 0, stream>>>(h, W_all, b_eff, dst, qb, kv8, deg);
    scan1<<<20, 1024, 0, stream>>>(deg, off, bsum);
    scan2<<<20, 1024, 0, stream>>>(bsum, off, cur);
    scatter_edges<<<NE / 256, 256, 0, stream>>>(dst, src, cur, esrc);
    aggregate<<<MPAD / 4, 256, 0, stream>>>(qb, kv8, off, esrc, t_bf);
    gemm_out<<<dim3(314, 4), 256, 0, stream>>>(t_bf, Wa_bf, ba, h, skip, out);
}

// Round 7
// 114.571 us; speedup vs baseline: 1.7249x; 1.0365x over previous
//
#include <hip/hip_runtime.h>
#include <hip/hip_bf16.h>
#include <math.h>

// HGT layer, MI355X. Pipeline (6 dispatches):
//  prep0        : zero deg || fold rel_att/rel_msg (+rel_pri*log2e/sqrt(dk)) into Wk/Wv
//                 -> W_all[768,256] bf16 || cast Wa -> bf16
//  gemm_qkv     : blocks 0-941: [MPAD,768] = cast_bf16(h) @ W_all^T + b_eff.
//                 K-loop LDS tiles XOR-swizzled (T2; A swizzled ds_write, B pre-swizzled
//                 global source for global_load_lds). Epilogue: acc -> LDS (swizzled)
//                 -> coalesced wide stores (16B for q bf16, 8B units for k/v fp8
//                 interleaved layout). blocks 942-2191: deg histogram.
//  scan1/scan2  : 20-block parallel exclusive scan of deg -> off/cur
//  scatter      : CSR scatter (stores src per slot)
//  aggregate    : 1 wave/node, half-wave per edge, ONE uint4 (16B) k+v load per lane
//                 per edge, 16 edges/iter, tail edges exec-masked.
//  gemm_out     : 64x64 tiles, swizzled LDS; out = (t_bf @ Wa^T + ba)*alpha + h*(1-alpha)

#define NN   20000
#define NE   320000
#define MPAD 20096   // 157*128 = 314*64

typedef unsigned short u16;
typedef unsigned char  u8;
typedef __bf16 bf16x8 __attribute__((ext_vector_type(8)));
typedef u16    u16x8  __attribute__((ext_vector_type(8)));
typedef float  f32x4  __attribute__((ext_vector_type(4)));

__device__ __forceinline__ float bf2f(u16 x) {
    union { float f; unsigned u; } c; c.u = ((unsigned)x) << 16; return c.f;
}
__device__ __forceinline__ u16 f2bf(float f) {
    union { float f; unsigned u; } c; c.f = f;
    unsigned r = c.u + 0x7fffu + ((c.u >> 16) & 1u);
    return (u16)(r >> 16);
}

#if __has_builtin(__builtin_amdgcn_cvt_pk_fp8_f32) && __has_builtin(__builtin_amdgcn_cvt_pk_f32_fp8)
#define HWFP8 1
#else
#define HWFP8 0
#endif

__device__ __forceinline__ u8 f2fp8(float x) {
#if HWFP8
    return (u8)(__builtin_amdgcn_cvt_pk_fp8_f32(x, x, 0, false) & 0xff);
#else
    if (x != x) return 0x7f;
    unsigned sg = (x < 0.f) ? 0x80u : 0u;
    float a = fabsf(x); if (a > 448.f) a = 448.f;
    if (a < 0.015625f) {
        int m = (int)rintf(a * 512.f);
        if (m > 7) return (u8)(sg | 0x08);
        return (u8)(sg | m);
    }
    int e; (void)frexpf(a, &e);
    int p = e - 1;
    float mant = a * exp2f((float)(-p));
    int m = (int)rintf((mant - 1.f) * 8.f);
    int ef = p + 7;
    if (m == 8) { m = 0; ef++; }
    if (ef > 15) { ef = 15; m = 6; }
    return (u8)(sg | (ef << 3) | m);
#endif
}

__device__ __forceinline__ void fp8x4_dec(unsigned w, float* o) {
#if HWFP8
    auto lo = __builtin_amdgcn_cvt_pk_f32_fp8(w, false);
    auto hi = __builtin_amdgcn_cvt_pk_f32_fp8(w, true);
    o[0] = lo[0]; o[1] = lo[1]; o[2] = hi[0]; o[3] = hi[1];
#else
    #pragma unroll
    for (int j = 0; j < 4; ++j) {
        u8 b = (w >> (8 * j)) & 0xff;
        unsigned e = (b >> 3) & 15, m = b & 7;
        float v;
        if (e) { union { unsigned u; float f; } c; c.u = ((e + 120) << 23) | (m << 20); v = c.f; }
        else v = (float)m * 0.001953125f;
        o[j] = (b & 0x80) ? -v : v;
    }
#endif
}

__device__ __forceinline__ float fast_exp2(float x) {
#if __has_builtin(__builtin_amdgcn_exp2f)
    return __builtin_amdgcn_exp2f(x);
#else
    return exp2f(x);
#endif
}

__device__ __forceinline__ void gload_lds16(const void* g, void* l) {
    __builtin_amdgcn_global_load_lds(
        (const __attribute__((address_space(1))) unsigned*)g,
        (__attribute__((address_space(3))) unsigned*)l, 16, 0, 0);
}

// ---------------------------------------------------------------- prep0: zero deg || weights
__global__ void prep0(const float* __restrict__ Wq, const float* __restrict__ bq,
                      const float* __restrict__ Wk, const float* __restrict__ bk,
                      const float* __restrict__ Wv, const float* __restrict__ bv,
                      const float* __restrict__ Wa,
                      const float* __restrict__ rel_att, const float* __restrict__ rel_msg,
                      const float* __restrict__ rel_pri,
                      u16* __restrict__ W_all, float* __restrict__ b_eff,
                      u16* __restrict__ Wa_bf, int* __restrict__ deg)
{
    const int bid = blockIdx.x, t = threadIdx.x;
    if (bid < 20) {
        const int i = bid * 256 + t;
        if (i < 5024) *(int4*)(deg + i * 4) = make_int4(0, 0, 0, 0);
    } else if (bid < 788) {
        const int row = bid - 20, col = t;
        float val;
        if (row < 256) {
            val = Wq[row * 256 + col];
            if (col == 0) b_eff[row] = bq[row];
        } else if (row < 512) {
            const int r = row - 256, hh = r >> 5, e = r & 31;
            // rel_pri / sqrt(32) * log2(e) -> aggregate uses exp2 directly
            const float s = rel_pri[hh] * 0.17677669529663687f * 1.4426950408889634f;
            float acc = 0.f;
            for (int d = 0; d < 32; ++d)
                acc += rel_att[hh * 1024 + d * 32 + e] * Wk[(hh * 32 + d) * 256 + col];
            val = acc * s;
            if (col == 0) {
                float b = 0.f;
                for (int d = 0; d < 32; ++d) b += rel_att[hh * 1024 + d * 32 + e] * bk[hh * 32 + d];
                b_eff[row] = b * s;
            }
        } else {
            const int r = row - 512, hh = r >> 5, e = r & 31;
            float acc = 0.f;
            for (int d = 0; d < 32; ++d)
                acc += rel_msg[hh * 1024 + d * 32 + e] * Wv[(hh * 32 + d) * 256 + col];
            val = acc;
            if (col == 0) {
                float b = 0.f;
                for (int d = 0; d < 32; ++d) b += rel_msg[hh * 1024 + d * 32 + e] * bv[hh * 32 + d];
                b_eff[row] = b;
            }
        }
        W_all[row * 256 + col] = f2bf(val);
    } else {
        const int idx = (bid - 788) * 256 + t;
        Wa_bf[idx] = f2bf(Wa[idx]);
    }
}

// ---------------------------------------------------------------- GEMM qkv + histogram
// K-loop LDS layout: At/Bt [128 rows][8 chunks of 8 elems]; physical chunk = logical ^ (row&7).
// Epilogue LDS: [128 rows][16 chunks]; physical chunk = logical ^ (row&15).
__global__ __launch_bounds__(256) void gemm_qkv(
    const float* __restrict__ h, const u16* __restrict__ B,
    const float* __restrict__ bias, const int* __restrict__ dst,
    u16* __restrict__ qb, u8* __restrict__ kv8, int* __restrict__ deg)
{
    if (blockIdx.x >= 942) {   // histogram part
        const int e = (blockIdx.x - 942) * 256 + threadIdx.x;
        if (e < NE) atomicAdd(&deg[dst[e]], 1);
        return;
    }
    __shared__ u16 LDS[128 * 128];          // 32KB: K-loop At|Bt, epilogue C-tile
    u16* At = LDS;
    u16* Bt = LDS + 128 * 64;
    const int t = threadIdx.x;
    const int wave = t >> 6, lane = t & 63;
    const int row0 = (blockIdx.x % 157) * 128, col0 = (blockIdx.x / 157) * 128;
    const int cb = blockIdx.x / 157;        // 0,1=q  2,3=k  4,5=v
    const int wm = (wave >> 1) * 64, wn = (wave & 1) * 64;
    const int cl = lane & 15, rh = lane >> 4;
    const int srow = t >> 3;                // staging row (t>>3), +32 per r
    const int lchunk = t & 7;               // logical 16B chunk this thread loads
    const int swz = (t >> 3) & 7;           // row&7 of the staged row
    const int scol = lchunk * 8;            // A: load logical chunk, write swizzled
    const int sc_swz = (lchunk ^ swz) * 8;  // B: fetch swizzled source, write linear

    f32x4 acc[4][4] = {};

    for (int k0 = 0; k0 < 256; k0 += 64) {
        __syncthreads();
        #pragma unroll
        for (int r = 0; r < 4; ++r) {
            const int rT = r * 32 + srow;
            const int grow = row0 + rT;
            u16x8 w8 = (u16x8)0;
            if (grow < NN) {
                const float4 f0 = *(const float4*)(h + (size_t)grow * 256 + k0 + scol);
                const float4 f1 = *(const float4*)(h + (size_t)grow * 256 + k0 + scol + 4);
                w8[0] = f2bf(f0.x); w8[1] = f2bf(f0.y); w8[2] = f2bf(f0.z); w8[3] = f2bf(f0.w);
                w8[4] = f2bf(f1.x); w8[5] = f2bf(f1.y); w8[6] = f2bf(f1.z); w8[7] = f2bf(f1.w);
            }
            *(u16x8*)&At[rT * 64 + (lchunk ^ swz) * 8] = w8;   // swizzled ds_write
            gload_lds16(B + (size_t)(col0 + rT) * 256 + k0 + sc_swz,
                        &Bt[(r * 256 + wave * 64) * 8]);       // linear dest, swz source
        }
        __syncthreads();
        #pragma unroll
        for (int kk = 0; kk < 64; kk += 32) {
            const int kc = kk >> 3;         // logical chunk base: 0 or 4
            bf16x8 af[4], bb[4];
            #pragma unroll
            for (int m = 0; m < 4; ++m) {
                const int ar = wm + 16 * m + cl;
                af[m] = *(const bf16x8*)&At[ar * 64 + (((kc + rh) ^ (ar & 7)) * 8)];
            }
            #pragma unroll
            for (int n = 0; n < 4; ++n) {
                const int br = wn + 16 * n + cl;
                bb[n] = *(const bf16x8*)&Bt[br * 64 + (((kc + rh) ^ (br & 7)) * 8)];
            }
            #pragma unroll
            for (int m = 0; m < 4; ++m)
                #pragma unroll
                for (int n = 0; n < 4; ++n)
                    acc[m][n] = __builtin_amdgcn_mfma_f32_16x16x32_bf16(af[m], bb[n], acc[m][n], 0, 0, 0);
        }
    }

    // ---- epilogue: acc -> LDS (swizzled) -> coalesced global stores
    __syncthreads();                        // last k-step's LDS reads done
    if (cb < 2) {
        // q: bf16 tile [128][128] in LDS
        #pragma unroll
        for (int n = 0; n < 4; ++n) {
            const int col = wn + 16 * n + cl;
            const float bv = bias[col0 + col];
            #pragma unroll
            for (int m = 0; m < 4; ++m) {
                const int rowb = wm + 16 * m + 4 * rh;
                #pragma unroll
                for (int r = 0; r < 4; ++r) {
                    const int row = rowb + r;
                    LDS[row * 128 + ((((col >> 3) ^ (row & 15)) << 3) | (col & 7))] =
                        f2bf(acc[m][n][r] + bv);
                }
            }
        }
        __syncthreads();
        #pragma unroll
        for (int it = 0; it < 8; ++it) {
            const int u = it * 256 + t;
            const int row = u >> 4, lc = u & 15;
            *(u16x8*)(qb + (size_t)(row0 + row) * 256 + col0 + lc * 8) =
                *(const u16x8*)&LDS[row * 128 + ((lc ^ (row & 15)) << 3)];
        }
    } else {
        // k/v: fp8 tile [128][128] bytes in LDS
        u8* Cs8 = (u8*)LDS;
        const int kvsel = (cb >= 4) ? 1 : 0;
        const int dbase = (cb - 2 - kvsel * 2) * 128;   // 0 or 128
        #pragma unroll
        for (int n = 0; n < 4; ++n) {
            const int col = wn + 16 * n + cl;
            const float bv = bias[col0 + col];
            #pragma unroll
            for (int m = 0; m < 4; ++m) {
                const int rowb = wm + 16 * m + 4 * rh;
                #pragma unroll
                for (int r = 0; r < 4; ++r) {
                    const int row = rowb + r;
                    Cs8[row * 128 + ((((col >> 3) ^ (row & 15)) << 3) | (col & 7))] =
                        f2fp8(acc[m][n][r] + bv);
                }
            }
        }
        __syncthreads();
        #pragma unroll
        for (int it = 0; it < 8; ++it) {
            const int u = it * 256 + t;
            const int row = u >> 4, lc = u & 15;
            const uint2 val = *(const uint2*)&Cs8[row * 128 + ((lc ^ (row & 15)) << 3)];
            *(uint2*)(kv8 + (size_t)(row0 + row) * 512 +
                      (size_t)(((dbase >> 3) + lc) << 4) + kvsel * 8) = val;
        }
    }
}

// ---------------------------------------------------------------- GEMM out (64x64 tiles, fp32 out)
__global__ __launch_bounds__(256) void gemm_out(
    const u16* __restrict__ A, const u16* __restrict__ B,
    const float* __restrict__ bias, const float* __restrict__ hres,
    const float* __restrict__ skip, float* __restrict__ C)
{
    __shared__ u16 At[64 * 64];
    __shared__ u16 Bt[64 * 64];
    const int t = threadIdx.x;
    const int wave = t >> 6, lane = t & 63;
    const int row0 = blockIdx.x * 64, col0 = blockIdx.y * 64;
    const int wm = (wave >> 1) * 32, wn = (wave & 1) * 32;
    const int cl = lane & 15, rh = lane >> 4;
    const int srow = t >> 3;
    const int sc_swz = (((t & 7) ^ ((t >> 3) & 7))) * 8;   // pre-swizzled source col

    f32x4 acc[2][2] = {};

    for (int k0 = 0; k0 < 256; k0 += 64) {
        __syncthreads();
        #pragma unroll
        for (int r = 0; r < 2; ++r) {
            const int rowT = r * 32 + srow;
            gload_lds16(A + (size_t)(row0 + rowT) * 256 + k0 + sc_swz, &At[(r * 2048 + wave * 512)]);
            gload_lds16(B + (size_t)(col0 + rowT) * 256 + k0 + sc_swz, &Bt[(r * 2048 + wave * 512)]);
        }
        __syncthreads();
        #pragma unroll
        for (int kk = 0; kk < 64; kk += 32) {
            const int kc = kk >> 3;
            bf16x8 af[2], bb[2];
            #pragma unroll
            for (int m = 0; m < 2; ++m) {
                const int ar = wm + 16 * m + cl;
                af[m] = *(const bf16x8*)&At[ar * 64 + (((kc + rh) ^ (ar & 7)) * 8)];
            }
            #pragma unroll
            for (int n = 0; n < 2; ++n) {
                const int br = wn + 16 * n + cl;
                bb[n] = *(const bf16x8*)&Bt[br * 64 + (((kc + rh) ^ (br & 7)) * 8)];
            }
            #pragma unroll
            for (int m = 0; m < 2; ++m)
                #pragma unroll
                for (int n = 0; n < 2; ++n)
                    acc[m][n] = __builtin_amdgcn_mfma_f32_16x16x32_bf16(af[m], bb[n], acc[m][n], 0, 0, 0);
        }
    }
    const float alpha = 1.f / (1.f + __expf(-skip[0]));
    const float beta = 1.f - alpha;
    #pragma unroll
    for (int n = 0; n < 2; ++n) {
        const int col = col0 + wn + 16 * n + cl;
        const float bv = bias[col];
        #pragma unroll
        for (int m = 0; m < 2; ++m) {
            const int rowb = row0 + wm + 16 * m + 4 * rh;
            #pragma unroll
            for (int r = 0; r < 4; ++r) {
                const int row = rowb + r;
                if (row < NN)
                    C[(size_t)row * 256 + col] =
                        (acc[m][n][r] + bv) * alpha + hres[(size_t)row * 256 + col] * beta;
            }
        }
    }
}

// ---------------------------------------------------------------- parallel scan (20 blocks)
__global__ __launch_bounds__(1024) void scan1(const int* __restrict__ deg,
                                              int* __restrict__ off, int* __restrict__ bsum)
{
    __shared__ int wsum[16];
    __shared__ int wpre[16];
    const int t = threadIdx.x, b = blockIdx.x;
    const int i = b * 1024 + t;
    const int lane = t & 63, wv = t >> 6;
    const int v = (i < NN) ? deg[i] : 0;
    int s = v;
    #pragma unroll
    for (int o = 1; o < 64; o <<= 1) {
        const int u = __shfl_up(s, o);
        if (lane >= o) s += u;
    }
    if (lane == 63) wsum[wv] = s;
    __syncthreads();
    if (wv == 0) {
        const int x = (lane < 16) ? wsum[lane] : 0;
        int sx = x;
        #pragma unroll
        for (int o = 1; o < 16; o <<= 1) {
            const int u = __shfl_up(sx, o);
            if (lane >= o) sx += u;
        }
        if (lane < 16) wpre[lane] = sx - x;
    }
    __syncthreads();
    const int incl = s + wpre[wv];
    if (i < NN) off[i] = incl - v;      // block-local exclusive
    if (t == 1023) bsum[b] = incl;      // block total
}

__global__ __launch_bounds__(1024) void scan2(const int* __restrict__ bsum,
                                              int* __restrict__ off, int* __restrict__ cur)
{
    __shared__ int pre;
    const int t = threadIdx.x, b = blockIdx.x;
    const int i = b * 1024 + t;
    if (t == 0) {
        int p = 0;
        for (int j = 0; j < b; ++j) p += bsum[j];
        pre = p;
    }
    __syncthreads();
    if (i < NN) {
        const int o = off[i] + pre;
        off[i] = o; cur[i] = o;
    }
    if (b == 19 && t == 0) off[NN] = pre + bsum[19];
}

__global__ void scatter_edges(const int* __restrict__ dst, const int* __restrict__ src,
                              int* __restrict__ cur, int* __restrict__ esrc)
{
    const int e = blockIdx.x * 256 + threadIdx.x;
    if (e < NE) {
        const int p = atomicAdd(&cur[dst[e]], 1);
        esrc[p] = src[e];
    }
}

// ---------------------------------------------------------------- aggregation (1 wave / node)
__device__ __forceinline__ void agg_edge(const u8* __restrict__ kv8, int id,
                                         const float* qf, int sl, float& z, float* acc)
{
    const uint4 w = *(const uint4*)(kv8 + (size_t)id * 512 + sl * 16);
    float kf[8], vf[8];
    fp8x4_dec(w.x, kf); fp8x4_dec(w.y, kf + 4);
    float s = 0.f;
    #pragma unroll
    for (int j = 0; j < 8; ++j) s += qf[j] * kf[j];
    s += __shfl_xor(s, 1);
    s += __shfl_xor(s, 2);             // 4 sub-lanes = one head's 32 dims
    const float ex = fast_exp2(s);     // log2e folded into k
    z += ex;
    fp8x4_dec(w.z, vf); fp8x4_dec(w.w, vf + 4);
    #pragma unroll
    for (int j = 0; j < 8; ++j) acc[j] += ex * vf[j];
}

__global__ __launch_bounds__(256) void aggregate(
    const u16* __restrict__ qb, const u8* __restrict__ kv8, const int* __restrict__ off,
    const int* __restrict__ esrc, u16* __restrict__ tout)
{
    const int wid = blockIdx.x * 4 + (threadIdx.x >> 6);
    const int lane = threadIdx.x & 63;
    const int half = lane >> 5, sl = lane & 31;
    if (wid >= MPAD) return;
    if (wid >= NN) {                   // zero pad rows for the downstream GEMM
        if (half == 0) *(u16x8*)(tout + (size_t)wid * 256 + sl * 8) = (u16x8)0;
        return;
    }
    const u16x8 qv = *(const u16x8*)(qb + (size_t)wid * 256 + sl * 8);
    float qf[8];
    #pragma unroll
    for (int j = 0; j < 8; ++j) qf[j] = bf2f(qv[j]);
    float acc[8] = {0.f, 0.f, 0.f, 0.f, 0.f, 0.f, 0.f, 0.f};
    float z = 0.f;
    const int e0 = off[wid], e1 = off[wid + 1];
    for (int c0 = e0; c0 < e1; c0 += 64) {
        const int cnt = min(64, e1 - c0);
        const int jj = c0 + lane;
        const int myid = (jj < e1) ? esrc[jj] : 0;   // chunk ids in registers
        for (int i = 0; i < cnt; i += 16) {          // 16 edges / iter (8 per half)
            int ii[8], idv[8];
            #pragma unroll
            for (int j = 0; j < 8; ++j) {
                ii[j] = i + 2 * j + half;
                idv[j] = __shfl(myid, ii[j]);
            }
            #pragma unroll
            for (int j = 0; j < 8; ++j)
                if (ii[j] < cnt)       // uniform per half-wave: masks off the LOAD too
                    agg_edge(kv8, idv[j], qf, sl, z, acc);
        }
    }
    #pragma unroll
    for (int j = 0; j < 8; ++j) acc[j] += __shfl_xor(acc[j], 32);
    z += __shfl_xor(z, 32);
    if (half == 0) {
        const float rz = (z > 0.f) ? 1.f / z : 0.f;
        u16x8 o;
        #pragma unroll
        for (int j = 0; j < 8; ++j) o[j] = f2bf(acc[j] * rz);
        *(u16x8*)(tout + (size_t)wid * 256 + sl * 8) = o;
    }
}

// ---------------------------------------------------------------- launch
extern "C" void kernel_launch(void* const* d_in, const int* in_sizes, int n_in,
                              void* d_out, int out_size, void* d_ws, size_t ws_size,
                              hipStream_t stream)
{
    const float* h   = (const float*)d_in[0];
    const int*   src = (const int*)d_in[1];
    const int*   dst = (const int*)d_in[2];
    const float* Wk  = (const float*)d_in[3];
    const float* bk  = (const float*)d_in[4];
    const float* Wq  = (const float*)d_in[5];
    const float* bq  = (const float*)d_in[6];
    const float* Wv  = (const float*)d_in[7];
    const float* bv  = (const float*)d_in[8];
    const float* Wa  = (const float*)d_in[9];
    const float* ba  = (const float*)d_in[10];
    const float* rel_att = (const float*)d_in[11];
    const float* rel_msg = (const float*)d_in[12];
    const float* rel_pri = (const float*)d_in[13];
    const float* skip    = (const float*)d_in[14];
    float* out = (float*)d_out;

    char* w = (char*)d_ws;
    u16*   W_all = (u16*)(w + 0);         //    393,216
    float* b_eff = (float*)(w + 393216);  //      3,072 (+pad)
    u16*   Wa_bf = (u16*)(w + 396288);    //    131,072
    u16*   qb    = (u16*)(w + 527360);    // 10,289,152
    u8*    kv8   = (u8*)(w + 10816512);   // 10,289,152
    u16*   t_bf  = (u16*)(w + 21105664);  // 10,289,152
    int*   deg   = (int*)(w + 31394816);  //     80,384 (20096 ints)
    int*   off   = (int*)(w + 31475200);  //     80,384
    int*   cur   = (int*)(w + 31555584);  //     80,384
    int*   bsum  = (int*)(w + 31635968);  //        128
    int*   esrc  = (int*)(w + 31636096);  //  1,280,000

    prep0<<<1044, 256, 0, stream>>>(Wq, bq, Wk, bk, Wv, bv, Wa,
                                    rel_att, rel_msg, rel_pri,
                                    W_all, b_eff, Wa_bf, deg);
    gemm_qkv<<<942 + 1250, 256, 0, stream>>>(h, W_all, b_eff, dst, qb, kv8, deg);
    scan1<<<20, 1024, 0, stream>>>(deg, off, bsum);
    scan2<<<20, 1024, 0, stream>>>(bsum, off, cur);
    scatter_edges<<<NE / 256, 256, 0, stream>>>(dst, src, cur, esrc);
    aggregate<<<MPAD / 4, 256, 0, stream>>>(qb, kv8, off, esrc, t_bf);
    gemm_out<<<dim3(314, 4), 256, 0, stream>>>(t_bf, Wa_bf, ba, h, skip, out);
}

// Round 8
// 107.576 us; speedup vs baseline: 1.8370x; 1.0650x over previous
//
#include <hip/hip_runtime.h>
#include <hip/hip_bf16.h>
#include <math.h>

// HGT layer, MI355X. Pipeline (6 dispatches):
//  prep0        : zero deg || fold rel_att/rel_msg into Wk/Wv -> W_all[768,256] bf16
//                 (rows: 0-255 q; 256+128g+[0,64) = k dims [64g,64g+64); +[64,128) = v dims)
//                 || cast Wa -> bf16
//  gemm_qkv     : virtual blocks 0-959: [MPAD,768] = cast_bf16(h) @ W_all^T + b_eff.
//                 XCD-affinity swizzle: all 6 col-tiles of a row-block share bid&7 ->
//                 A re-reads hit the local L2. kv col-tiles paired (k+v same chunk range)
//                 -> epilogue stores full 16B units (no partial-sector RMW).
//                 blocks 960+: deg histogram.
//  scan1/scan2  : 20-block parallel exclusive scan of deg -> off/cur
//  scatter      : CSR scatter (stores src per slot)
//  aggregate    : 1 wave/node, half-wave per edge, ONE uint4 (16B) k+v load per lane
//                 per edge, 16 edges/iter, tail edges exec-masked.
//  gemm_out     : 64x64 tiles, swizzled LDS + XCD-affinity grid; residual epilogue.

#define NN   20000
#define NE   320000
#define MPAD 20096   // 157*128 = 314*64

typedef unsigned short u16;
typedef unsigned char  u8;
typedef __bf16 bf16x8 __attribute__((ext_vector_type(8)));
typedef u16    u16x8  __attribute__((ext_vector_type(8)));
typedef float  f32x4  __attribute__((ext_vector_type(4)));

__device__ __forceinline__ float bf2f(u16 x) {
    union { float f; unsigned u; } c; c.u = ((unsigned)x) << 16; return c.f;
}
__device__ __forceinline__ u16 f2bf(float f) {
    union { float f; unsigned u; } c; c.f = f;
    unsigned r = c.u + 0x7fffu + ((c.u >> 16) & 1u);
    return (u16)(r >> 16);
}

#if __has_builtin(__builtin_amdgcn_cvt_pk_fp8_f32) && __has_builtin(__builtin_amdgcn_cvt_pk_f32_fp8)
#define HWFP8 1
#else
#define HWFP8 0
#endif

__device__ __forceinline__ u8 f2fp8(float x) {
#if HWFP8
    return (u8)(__builtin_amdgcn_cvt_pk_fp8_f32(x, x, 0, false) & 0xff);
#else
    if (x != x) return 0x7f;
    unsigned sg = (x < 0.f) ? 0x80u : 0u;
    float a = fabsf(x); if (a > 448.f) a = 448.f;
    if (a < 0.015625f) {
        int m = (int)rintf(a * 512.f);
        if (m > 7) return (u8)(sg | 0x08);
        return (u8)(sg | m);
    }
    int e; (void)frexpf(a, &e);
    int p = e - 1;
    float mant = a * exp2f((float)(-p));
    int m = (int)rintf((mant - 1.f) * 8.f);
    int ef = p + 7;
    if (m == 8) { m = 0; ef++; }
    if (ef > 15) { ef = 15; m = 6; }
    return (u8)(sg | (ef << 3) | m);
#endif
}

__device__ __forceinline__ void fp8x4_dec(unsigned w, float* o) {
#if HWFP8
    auto lo = __builtin_amdgcn_cvt_pk_f32_fp8(w, false);
    auto hi = __builtin_amdgcn_cvt_pk_f32_fp8(w, true);
    o[0] = lo[0]; o[1] = lo[1]; o[2] = hi[0]; o[3] = hi[1];
#else
    #pragma unroll
    for (int j = 0; j < 4; ++j) {
        u8 b = (w >> (8 * j)) & 0xff;
        unsigned e = (b >> 3) & 15, m = b & 7;
        float v;
        if (e) { union { unsigned u; float f; } c; c.u = ((e + 120) << 23) | (m << 20); v = c.f; }
        else v = (float)m * 0.001953125f;
        o[j] = (b & 0x80) ? -v : v;
    }
#endif
}

__device__ __forceinline__ float fast_exp2(float x) {
#if __has_builtin(__builtin_amdgcn_exp2f)
    return __builtin_amdgcn_exp2f(x);
#else
    return exp2f(x);
#endif
}

__device__ __forceinline__ void gload_lds16(const void* g, void* l) {
    __builtin_amdgcn_global_load_lds(
        (const __attribute__((address_space(1))) unsigned*)g,
        (__attribute__((address_space(3))) unsigned*)l, 16, 0, 0);
}

// ---------------------------------------------------------------- prep0: zero deg || weights
// W_all row r: r<256 -> q dim r.  r>=256: i=r-256, g=i>>7, o=i&127;
//   o<64 -> k dim d=64g+o (rel_att fold, * rel_pri*log2e/sqrt(32));
//   o>=64 -> v dim d=64g+o-64 (rel_msg fold).
__global__ void prep0(const float* __restrict__ Wq, const float* __restrict__ bq,
                      const float* __restrict__ Wk, const float* __restrict__ bk,
                      const float* __restrict__ Wv, const float* __restrict__ bv,
                      const float* __restrict__ Wa,
                      const float* __restrict__ rel_att, const float* __restrict__ rel_msg,
                      const float* __restrict__ rel_pri,
                      u16* __restrict__ W_all, float* __restrict__ b_eff,
                      u16* __restrict__ Wa_bf, int* __restrict__ deg)
{
    const int bid = blockIdx.x, t = threadIdx.x;
    if (bid < 20) {
        const int i = bid * 256 + t;
        if (i < 5024) *(int4*)(deg + i * 4) = make_int4(0, 0, 0, 0);
    } else if (bid < 788) {
        const int row = bid - 20, col = t;
        float val;
        if (row < 256) {
            val = Wq[row * 256 + col];
            if (col == 0) b_eff[row] = bq[row];
        } else {
            const int i = row - 256, g = i >> 7, o = i & 127;
            const bool isk = (o < 64);
            const int d = 64 * g + (isk ? o : o - 64);
            const int hh = d >> 5, e = d & 31;
            if (isk) {
                const float s = rel_pri[hh] * 0.17677669529663687f * 1.4426950408889634f;
                float acc = 0.f;
                for (int dd = 0; dd < 32; ++dd)
                    acc += rel_att[hh * 1024 + dd * 32 + e] * Wk[(hh * 32 + dd) * 256 + col];
                val = acc * s;
                if (col == 0) {
                    float b = 0.f;
                    for (int dd = 0; dd < 32; ++dd) b += rel_att[hh * 1024 + dd * 32 + e] * bk[hh * 32 + dd];
                    b_eff[row] = b * s;
                }
            } else {
                float acc = 0.f;
                for (int dd = 0; dd < 32; ++dd)
                    acc += rel_msg[hh * 1024 + dd * 32 + e] * Wv[(hh * 32 + dd) * 256 + col];
                val = acc;
                if (col == 0) {
                    float b = 0.f;
                    for (int dd = 0; dd < 32; ++dd) b += rel_msg[hh * 1024 + dd * 32 + e] * bv[hh * 32 + dd];
                    b_eff[row] = b;
                }
            }
        }
        W_all[row * 256 + col] = f2bf(val);
    } else {
        const int idx = (bid - 788) * 256 + t;
        Wa_bf[idx] = f2bf(Wa[idx]);
    }
}

// ---------------------------------------------------------------- GEMM qkv + histogram
// Virtual GEMM blocks [0,960): xcd=bid&7, slot=bid>>3; rb=(slot%20)*8+xcd (guard<157),
// cb=slot/20 (0,1=q; 2..5=kv group g=cb-2). blocks >=960: histogram.
__global__ __launch_bounds__(256) void gemm_qkv(
    const float* __restrict__ h, const u16* __restrict__ B,
    const float* __restrict__ bias, const int* __restrict__ dst,
    u16* __restrict__ qb, u8* __restrict__ kv8, int* __restrict__ deg)
{
    if (blockIdx.x >= 960) {   // histogram part
        const int e = (blockIdx.x - 960) * 256 + threadIdx.x;
        if (e < NE) atomicAdd(&deg[dst[e]], 1);
        return;
    }
    const int xcd = blockIdx.x & 7, slot = blockIdx.x >> 3;
    const int rb = (slot % 20) * 8 + xcd;
    const int cb = slot / 20;
    if (rb >= 157) return;
    __shared__ u16 LDS[128 * 128];          // 32KB: K-loop At|Bt, epilogue C-tile
    u16* At = LDS;
    u16* Bt = LDS + 128 * 64;
    const int t = threadIdx.x;
    const int wave = t >> 6, lane = t & 63;
    const int row0 = rb * 128, col0 = cb * 128;
    const int wm = (wave >> 1) * 64, wn = (wave & 1) * 64;
    const int cl = lane & 15, rh = lane >> 4;
    const int srow = t >> 3;                // staging row (t>>3), +32 per r
    const int lchunk = t & 7;               // logical 16B chunk this thread loads
    const int swz = (t >> 3) & 7;           // row&7 of the staged row
    const int scol = lchunk * 8;            // A: load logical chunk, write swizzled
    const int sc_swz = (lchunk ^ swz) * 8;  // B: fetch swizzled source, write linear

    f32x4 acc[4][4] = {};

    for (int k0 = 0; k0 < 256; k0 += 64) {
        __syncthreads();
        #pragma unroll
        for (int r = 0; r < 4; ++r) {
            const int rT = r * 32 + srow;
            const int grow = row0 + rT;
            u16x8 w8 = (u16x8)0;
            if (grow < NN) {
                const float4 f0 = *(const float4*)(h + (size_t)grow * 256 + k0 + scol);
                const float4 f1 = *(const float4*)(h + (size_t)grow * 256 + k0 + scol + 4);
                w8[0] = f2bf(f0.x); w8[1] = f2bf(f0.y); w8[2] = f2bf(f0.z); w8[3] = f2bf(f0.w);
                w8[4] = f2bf(f1.x); w8[5] = f2bf(f1.y); w8[6] = f2bf(f1.z); w8[7] = f2bf(f1.w);
            }
            *(u16x8*)&At[rT * 64 + (lchunk ^ swz) * 8] = w8;   // swizzled ds_write
            gload_lds16(B + (size_t)(col0 + rT) * 256 + k0 + sc_swz,
                        &Bt[(r * 256 + wave * 64) * 8]);       // linear dest, swz source
        }
        __syncthreads();
        #pragma unroll
        for (int kk = 0; kk < 64; kk += 32) {
            const int kc = kk >> 3;         // logical chunk base: 0 or 4
            bf16x8 af[4], bb[4];
            #pragma unroll
            for (int m = 0; m < 4; ++m) {
                const int ar = wm + 16 * m + cl;
                af[m] = *(const bf16x8*)&At[ar * 64 + (((kc + rh) ^ (ar & 7)) * 8)];
            }
            #pragma unroll
            for (int n = 0; n < 4; ++n) {
                const int br = wn + 16 * n + cl;
                bb[n] = *(const bf16x8*)&Bt[br * 64 + (((kc + rh) ^ (br & 7)) * 8)];
            }
            #pragma unroll
            for (int m = 0; m < 4; ++m)
                #pragma unroll
                for (int n = 0; n < 4; ++n)
                    acc[m][n] = __builtin_amdgcn_mfma_f32_16x16x32_bf16(af[m], bb[n], acc[m][n], 0, 0, 0);
        }
    }

    // ---- epilogue: acc -> LDS (swizzled) -> coalesced global stores
    __syncthreads();                        // last k-step's LDS reads done
    if (cb < 2) {
        // q: bf16 tile [128][128] in LDS
        #pragma unroll
        for (int n = 0; n < 4; ++n) {
            const int col = wn + 16 * n + cl;
            const float bv = bias[col0 + col];
            #pragma unroll
            for (int m = 0; m < 4; ++m) {
                const int rowb = wm + 16 * m + 4 * rh;
                #pragma unroll
                for (int r = 0; r < 4; ++r) {
                    const int row = rowb + r;
                    LDS[row * 128 + ((((col >> 3) ^ (row & 15)) << 3) | (col & 7))] =
                        f2bf(acc[m][n][r] + bv);
                }
            }
        }
        __syncthreads();
        #pragma unroll
        for (int it = 0; it < 8; ++it) {
            const int u = it * 256 + t;
            const int row = u >> 4, lc = u & 15;
            *(u16x8*)(qb + (size_t)(row0 + row) * 256 + col0 + lc * 8) =
                *(const u16x8*)&LDS[row * 128 + ((lc ^ (row & 15)) << 3)];
        }
    } else {
        // kv pair tile: cols 0..63 = k dims [64g,64g+64), 64..127 = v dims [64g,64g+64)
        // byte pos within row's 128B group: k -> (o>>3)*16+(o&7); v -> (o>>3)*16+8+(o&7)
        u8* Cs8 = (u8*)LDS;
        const int g = cb - 2;
        #pragma unroll
        for (int n = 0; n < 4; ++n) {
            const int col = wn + 16 * n + cl;
            const float bv = bias[col0 + col];
            const int o = col & 63;
            const int p = ((o >> 3) << 4) + ((col < 64) ? 0 : 8) + (o & 7);
            #pragma unroll
            for (int m = 0; m < 4; ++m) {
                const int rowb = wm + 16 * m + 4 * rh;
                #pragma unroll
                for (int r = 0; r < 4; ++r) {
                    const int row = rowb + r;
                    Cs8[row * 128 + ((((p >> 3) ^ (row & 15)) << 3) | (p & 7))] =
                        f2fp8(acc[m][n][r] + bv);
                }
            }
        }
        __syncthreads();
        #pragma unroll
        for (int it = 0; it < 4; ++it) {    // 128 rows x 8 units of 16B
            const int u = it * 256 + t;
            const int row = u >> 3, un = u & 7;
            const uint2 a = *(const uint2*)&Cs8[row * 128 + (((2 * un) ^ (row & 15)) << 3)];
            const uint2 b = *(const uint2*)&Cs8[row * 128 + (((2 * un + 1) ^ (row & 15)) << 3)];
            *(uint4*)(kv8 + (size_t)(row0 + row) * 512 + g * 128 + un * 16) =
                make_uint4(a.x, a.y, b.x, b.y);
        }
    }
}

// ---------------------------------------------------------------- GEMM out (64x64 tiles)
// Virtual blocks [0,1280): xcd=bid&7, slot=bid>>3; rb=(slot%40)*8+xcd (guard<314), cb=slot/40.
__global__ __launch_bounds__(256) void gemm_out(
    const u16* __restrict__ A, const u16* __restrict__ B,
    const float* __restrict__ bias, const float* __restrict__ hres,
    const float* __restrict__ skip, float* __restrict__ C)
{
    const int xcd = blockIdx.x & 7, slot = blockIdx.x >> 3;
    const int rb = (slot % 40) * 8 + xcd;
    const int cbo = slot / 40;
    if (rb >= 314) return;
    __shared__ u16 At[64 * 64];
    __shared__ u16 Bt[64 * 64];
    const int t = threadIdx.x;
    const int wave = t >> 6, lane = t & 63;
    const int row0 = rb * 64, col0 = cbo * 64;
    const int wm = (wave >> 1) * 32, wn = (wave & 1) * 32;
    const int cl = lane & 15, rh = lane >> 4;
    const int srow = t >> 3;
    const int sc_swz = (((t & 7) ^ ((t >> 3) & 7))) * 8;   // pre-swizzled source col

    f32x4 acc[2][2] = {};

    for (int k0 = 0; k0 < 256; k0 += 64) {
        __syncthreads();
        #pragma unroll
        for (int r = 0; r < 2; ++r) {
            const int rowT = r * 32 + srow;
            gload_lds16(A + (size_t)(row0 + rowT) * 256 + k0 + sc_swz, &At[(r * 2048 + wave * 512)]);
            gload_lds16(B + (size_t)(col0 + rowT) * 256 + k0 + sc_swz, &Bt[(r * 2048 + wave * 512)]);
        }
        __syncthreads();
        #pragma unroll
        for (int kk = 0; kk < 64; kk += 32) {
            const int kc = kk >> 3;
            bf16x8 af[2], bb[2];
            #pragma unroll
            for (int m = 0; m < 2; ++m) {
                const int ar = wm + 16 * m + cl;
                af[m] = *(const bf16x8*)&At[ar * 64 + (((kc + rh) ^ (ar & 7)) * 8)];
            }
            #pragma unroll
            for (int n = 0; n < 2; ++n) {
                const int br = wn + 16 * n + cl;
                bb[n] = *(const bf16x8*)&Bt[br * 64 + (((kc + rh) ^ (br & 7)) * 8)];
            }
            #pragma unroll
            for (int m = 0; m < 2; ++m)
                #pragma unroll
                for (int n = 0; n < 2; ++n)
                    acc[m][n] = __builtin_amdgcn_mfma_f32_16x16x32_bf16(af[m], bb[n], acc[m][n], 0, 0, 0);
        }
    }
    const float alpha = 1.f / (1.f + __expf(-skip[0]));
    const float beta = 1.f - alpha;
    #pragma unroll
    for (int n = 0; n < 2; ++n) {
        const int col = col0 + wn + 16 * n + cl;
        const float bv = bias[col];
        #pragma unroll
        for (int m = 0; m < 2; ++m) {
            const int rowb = row0 + wm + 16 * m + 4 * rh;
            #pragma unroll
            for (int r = 0; r < 4; ++r) {
                const int row = rowb + r;
                if (row < NN)
                    C[(size_t)row * 256 + col] =
                        (acc[m][n][r] + bv) * alpha + hres[(size_t)row * 256 + col] * beta;
            }
        }
    }
}

// ---------------------------------------------------------------- parallel scan (20 blocks)
__global__ __launch_bounds__(1024) void scan1(const int* __restrict__ deg,
                                              int* __restrict__ off, int* __restrict__ bsum)
{
    __shared__ int wsum[16];
    __shared__ int wpre[16];
    const int t = threadIdx.x, b = blockIdx.x;
    const int i = b * 1024 + t;
    const int lane = t & 63, wv = t >> 6;
    const int v = (i < NN) ? deg[i] : 0;
    int s = v;
    #pragma unroll
    for (int o = 1; o < 64; o <<= 1) {
        const int u = __shfl_up(s, o);
        if (lane >= o) s += u;
    }
    if (lane == 63) wsum[wv] = s;
    __syncthreads();
    if (wv == 0) {
        const int x = (lane < 16) ? wsum[lane] : 0;
        int sx = x;
        #pragma unroll
        for (int o = 1; o < 16; o <<= 1) {
            const int u = __shfl_up(sx, o);
            if (lane >= o) sx += u;
        }
        if (lane < 16) wpre[lane] = sx - x;
    }
    __syncthreads();
    const int incl = s + wpre[wv];
    if (i < NN) off[i] = incl - v;      // block-local exclusive
    if (t == 1023) bsum[b] = incl;      // block total
}

__global__ __launch_bounds__(1024) void scan2(const int* __restrict__ bsum,
                                              int* __restrict__ off, int* __restrict__ cur)
{
    __shared__ int pre;
    const int t = threadIdx.x, b = blockIdx.x;
    const int i = b * 1024 + t;
    if (t == 0) {
        int p = 0;
        for (int j = 0; j < b; ++j) p += bsum[j];
        pre = p;
    }
    __syncthreads();
    if (i < NN) {
        const int o = off[i] + pre;
        off[i] = o; cur[i] = o;
    }
    if (b == 19 && t == 0) off[NN] = pre + bsum[19];
}

__global__ void scatter_edges(const int* __restrict__ dst, const int* __restrict__ src,
                              int* __restrict__ cur, int* __restrict__ esrc)
{
    const int e = blockIdx.x * 256 + threadIdx.x;
    if (e < NE) {
        const int p = atomicAdd(&cur[dst[e]], 1);
        esrc[p] = src[e];
    }
}

// ---------------------------------------------------------------- aggregation (1 wave / node)
__device__ __forceinline__ void agg_edge(const u8* __restrict__ kv8, int id,
                                         const float* qf, int sl, float& z, float* acc)
{
    const uint4 w = *(const uint4*)(kv8 + (size_t)id * 512 + sl * 16);
    float kf[8], vf[8];
    fp8x4_dec(w.x, kf); fp8x4_dec(w.y, kf + 4);
    float s = 0.f;
    #pragma unroll
    for (int j = 0; j < 8; ++j) s += qf[j] * kf[j];
    s += __shfl_xor(s, 1);
    s += __shfl_xor(s, 2);             // 4 sub-lanes = one head's 32 dims
    const float ex = fast_exp2(s);     // log2e folded into k
    z += ex;
    fp8x4_dec(w.z, vf); fp8x4_dec(w.w, vf + 4);
    #pragma unroll
    for (int j = 0; j < 8; ++j) acc[j] += ex * vf[j];
}

__global__ __launch_bounds__(256) void aggregate(
    const u16* __restrict__ qb, const u8* __restrict__ kv8, const int* __restrict__ off,
    const int* __restrict__ esrc, u16* __restrict__ tout)
{
    const int wid = blockIdx.x * 4 + (threadIdx.x >> 6);
    const int lane = threadIdx.x & 63;
    const int half = lane >> 5, sl = lane & 31;
    if (wid >= MPAD) return;
    if (wid >= NN) {                   // zero pad rows for the downstream GEMM
        if (half == 0) *(u16x8*)(tout + (size_t)wid * 256 + sl * 8) = (u16x8)0;
        return;
    }
    const u16x8 qv = *(const u16x8*)(qb + (size_t)wid * 256 + sl * 8);
    float qf[8];
    #pragma unroll
    for (int j = 0; j < 8; ++j) qf[j] = bf2f(qv[j]);
    float acc[8] = {0.f, 0.f, 0.f, 0.f, 0.f, 0.f, 0.f, 0.f};
    float z = 0.f;
    const int e0 = off[wid], e1 = off[wid + 1];
    for (int c0 = e0; c0 < e1; c0 += 64) {
        const int cnt = min(64, e1 - c0);
        const int jj = c0 + lane;
        const int myid = (jj < e1) ? esrc[jj] : 0;   // chunk ids in registers
        for (int i = 0; i < cnt; i += 16) {          // 16 edges / iter (8 per half)
            int ii[8], idv[8];
            #pragma unroll
            for (int j = 0; j < 8; ++j) {
                ii[j] = i + 2 * j + half;
                idv[j] = __shfl(myid, ii[j]);
            }
            #pragma unroll
            for (int j = 0; j < 8; ++j)
                if (ii[j] < cnt)       // uniform per half-wave: masks off the LOAD too
                    agg_edge(kv8, idv[j], qf, sl, z, acc);
        }
    }
    #pragma unroll
    for (int j = 0; j < 8; ++j) acc[j] += __shfl_xor(acc[j], 32);
    z += __shfl_xor(z, 32);
    if (half == 0) {
        const float rz = (z > 0.f) ? 1.f / z : 0.f;
        u16x8 o;
        #pragma unroll
        for (int j = 0; j < 8; ++j) o[j] = f2bf(acc[j] * rz);
        *(u16x8*)(tout + (size_t)wid * 256 + sl * 8) = o;
    }
}

// ---------------------------------------------------------------- launch
extern "C" void kernel_launch(void* const* d_in, const int* in_sizes, int n_in,
                              void* d_out, int out_size, void* d_ws, size_t ws_size,
                              hipStream_t stream)
{
    const float* h   = (const float*)d_in[0];
    const int*   src = (const int*)d_in[1];
    const int*   dst = (const int*)d_in[2];
    const float* Wk  = (const float*)d_in[3];
    const float* bk  = (const float*)d_in[4];
    const float* Wq  = (const float*)d_in[5];
    const float* bq  = (const float*)d_in[6];
    const float* Wv  = (const float*)d_in[7];
    const float* bv  = (const float*)d_in[8];
    const float* Wa  = (const float*)d_in[9];
    const float* ba  = (const float*)d_in[10];
    const float* rel_att = (const float*)d_in[11];
    const float* rel_msg = (const float*)d_in[12];
    const float* rel_pri = (const float*)d_in[13];
    const float* skip    = (const float*)d_in[14];
    float* out = (float*)d_out;

    char* w = (char*)d_ws;
    u16*   W_all = (u16*)(w + 0);         //    393,216
    float* b_eff = (float*)(w + 393216);  //      3,072 (+pad)
    u16*   Wa_bf = (u16*)(w + 396288);    //    131,072
    u16*   qb    = (u16*)(w + 527360);    // 10,289,152
    u8*    kv8   = (u8*)(w + 10816512);   // 10,289,152
    u16*   t_bf  = (u16*)(w + 21105664);  // 10,289,152
    int*   deg   = (int*)(w + 31394816);  //     80,384 (20096 ints)
    int*   off   = (int*)(w + 31475200);  //     80,384
    int*   cur   = (int*)(w + 31555584);  //     80,384
    int*   bsum  = (int*)(w + 31635968);  //        128
    int*   esrc  = (int*)(w + 31636096);  //  1,280,000

    prep0<<<1044, 256, 0, stream>>>(Wq, bq, Wk, bk, Wv, bv, Wa,
                                    rel_att, rel_msg, rel_pri,
                                    W_all, b_eff, Wa_bf, deg);
    gemm_qkv<<<960 + 1250, 256, 0, stream>>>(h, W_all, b_eff, dst, qb, kv8, deg);
    scan1<<<20, 1024, 0, stream>>>(deg, off, bsum);
    scan2<<<20, 1024, 0, stream>>>(bsum, off, cur);
    scatter_edges<<<NE / 256, 256, 0, stream>>>(dst, src, cur, esrc);
    aggregate<<<MPAD / 4, 256, 0, stream>>>(qb, kv8, off, esrc, t_bf);
    gemm_out<<<1280, 256, 0, stream>>>(t_bf, Wa_bf, ba, h, skip, out);
}